// Round 5
// baseline (1012.337 us; speedup 1.0000x reference)
//
#include <hip/hip_runtime.h>

#define N_NODES 200000
#define N_EDGES 3200000
#define N_GRAPHS 1024
#define HD 16
#define ALPHA_ 0.2f

#define BNODES 256                 // nodes per bucket (dst >> 8)
#define NBUCK 782                  // ceil(N_NODES/256)
#define CHUNKA 4096                // edges per pass-A block
#define NBLKA 782                  // ceil(N_EDGES/CHUNKA)
#define YCH 288                    // agg2 chunks per bucket (covers 4608 edges; +stride loop)

typedef unsigned long long u64;

// ---------- bucket sort by dst>>8 (no global atomics) ----------
__global__ __launch_bounds__(256) void hist_kernel(const int* __restrict__ dst,
                                                   int* __restrict__ blkhist) {
    __shared__ int hist[NBUCK];
    int t = threadIdx.x;
    for (int i = t; i < NBUCK; i += 256) hist[i] = 0;
    __syncthreads();
    int e0 = blockIdx.x * CHUNKA;
    int e1 = min(e0 + CHUNKA, N_EDGES);
    for (int e = e0 + t; e < e1; e += 256)
        atomicAdd(&hist[dst[e] >> 8], 1);
    __syncthreads();
    int* out = blkhist + (size_t)blockIdx.x * NBUCK;
    for (int i = t; i < NBUCK; i += 256) out[i] = hist[i];
}

__global__ __launch_bounds__(256) void scanA_kernel(int* __restrict__ blkhist,
                                                    int* __restrict__ bstart) {
    __shared__ int s[256];
    int u = blockIdx.x, t = threadIdx.x;
    int v[4];
    int sum = 0;
#pragma unroll
    for (int i = 0; i < 4; ++i) {
        int j = t * 4 + i;
        v[i] = (j < NBLKA) ? blkhist[(size_t)j * NBUCK + u] : 0;
        sum += v[i];
    }
    s[t] = sum;
    __syncthreads();
    for (int off = 1; off < 256; off <<= 1) {
        int x = (t >= off) ? s[t - off] : 0;
        __syncthreads();
        s[t] += x;
        __syncthreads();
    }
    int run = s[t] - sum;
#pragma unroll
    for (int i = 0; i < 4; ++i) {
        int j = t * 4 + i;
        if (j < NBLKA) blkhist[(size_t)j * NBUCK + u] = run;
        run += v[i];
    }
    if (t == 255) bstart[u] = s[255];
}

__global__ __launch_bounds__(256) void scanB_kernel(int* __restrict__ bstart) {
    __shared__ int s[256];
    int t = threadIdx.x;
    int v[4];
    int sum = 0;
#pragma unroll
    for (int i = 0; i < 4; ++i) {
        int j = t * 4 + i;
        v[i] = (j < NBUCK) ? bstart[j] : 0;
        sum += v[i];
    }
    s[t] = sum;
    __syncthreads();
    for (int off = 1; off < 256; off <<= 1) {
        int x = (t >= off) ? s[t - off] : 0;
        __syncthreads();
        s[t] += x;
        __syncthreads();
    }
    int run = s[t] - sum;
#pragma unroll
    for (int i = 0; i < 4; ++i) {
        int j = t * 4 + i;
        if (j < NBUCK) bstart[j] = run;
        run += v[i];
    }
    if (t == 255) bstart[NBUCK] = s[255];
}

// entry = (ea:32 | dlow:8 | src:18)
__global__ __launch_bounds__(256) void scatter_kernel(const int* __restrict__ src,
                                                      const int* __restrict__ dst,
                                                      const float* __restrict__ ea,
                                                      const int* __restrict__ blkhist,
                                                      const int* __restrict__ bstart,
                                                      u64* __restrict__ bucketed) {
    __shared__ int cursor[NBUCK];
    int t = threadIdx.x;
    const int* bo = blkhist + (size_t)blockIdx.x * NBUCK;
    for (int i = t; i < NBUCK; i += 256) cursor[i] = bstart[i] + bo[i];
    __syncthreads();
    int e0 = blockIdx.x * CHUNKA;
    int e1 = min(e0 + CHUNKA, N_EDGES);
    for (int e = e0 + t; e < e1; e += 256) {
        int d = dst[e];
        int u = d >> 8;
        int pos = atomicAdd(&cursor[u], 1);   // LDS atomic
        u64 ent = ((u64)__float_as_uint(ea[e]) << 32)
                | (unsigned)(src[e] | ((d & 255) << 18));
        bucketed[pos] = ent;
    }
}

// weighted degree -> dinv[n] and dx[n] = {dinv, dinv*x}
__global__ __launch_bounds__(256) void dinvB_kernel(const u64* __restrict__ bucketed,
                                                    const int* __restrict__ bstart,
                                                    const float* __restrict__ x,
                                                    float* __restrict__ dinv,
                                                    float2* __restrict__ dx) {
    __shared__ float wdeg[BNODES];
    int u = blockIdx.x, t = threadIdx.x;
    wdeg[t] = 0.f;
    __syncthreads();
    int b0 = bstart[u], b1 = bstart[u + 1];
    for (int i = b0 + t; i < b1; i += 256) {
        u64 ent = bucketed[i];
        atomicAdd(&wdeg[(int)((ent >> 18) & 255u)], __uint_as_float((unsigned)(ent >> 32)));
    }
    __syncthreads();
    int n = u * BNODES + t;
    if (n < N_NODES) {
        float dn = rsqrtf(wdeg[t] + 1.0f);
        dinv[n] = dn;
        dx[n] = make_float2(dn, dn * x[n]);
    }
}

// layer 0 scalar aggregation + in-place rewrite ea -> full weight w.
// base0[n] = sum_e w*x[s] + dinv^2 * x[n]
__global__ __launch_bounds__(512, 6) void agg0_kernel(u64* __restrict__ bucketed,
                                                      const int* __restrict__ bstart,
                                                      const float2* __restrict__ dx,
                                                      float* __restrict__ base0) {
    __shared__ float acc[BNODES];
    __shared__ float sd[BNODES], sdy[BNODES];
    int u = blockIdx.x, t = threadIdx.x;
    if (t < 256) {
        int n = u * BNODES + t;
        float2 d = (n < N_NODES) ? dx[n] : make_float2(0.f, 0.f);
        sd[t] = d.x;
        sdy[t] = d.y;
        acc[t] = 0.f;
    }
    __syncthreads();
    int b0 = bstart[u], b1 = bstart[u + 1];
    for (int i = b0 + (t << 2); i < b1; i += 2048) {
        u64 ent[4];
        float2 g[4];
#pragma unroll
        for (int k = 0; k < 4; ++k)
            if (i + k < b1) ent[k] = bucketed[i + k];
#pragma unroll
        for (int k = 0; k < 4; ++k)
            if (i + k < b1) g[k] = dx[(int)(ent[k] & 0x3ffffu)];
#pragma unroll
        for (int k = 0; k < 4; ++k)
            if (i + k < b1) {
                int dl = (int)((ent[k] >> 18) & 255u);
                float eav = __uint_as_float((unsigned)(ent[k] >> 32));
                float wd = eav * sd[dl];           // ea * dinv[d]
                float w = wd * g[k].x;             // full normalized weight
                bucketed[i + k] = ((u64)__float_as_uint(w) << 32)
                                | (unsigned)(ent[k] & 0x03ffffffu);
                atomicAdd(&acc[dl], wd * g[k].y);  // = w * x[s]
            }
    }
    __syncthreads();
    if (t >= 256) return;
    int n = u * BNODES + t;
    if (n < N_NODES) base0[n] = acc[t] + sd[t] * sdy[t];
}

// layer 1: gather only scalar base0[s] (L2-resident), recompute r0 on the fly.
// q[d] = sum w*r0[s] + dn^2*r0[d];  c[d] = sum w + dn^2
// h2 = relu((q@lw0 + c*lb0)@cwr0 + cb1) @ lw1 + lb1
__global__ __launch_bounds__(512, 6) void agg1_kernel(const u64* __restrict__ bucketed,
                                                      const int* __restrict__ bstart,
                                                      const float* __restrict__ base0,
                                                      const float* __restrict__ dinv,
                                                      const float* __restrict__ cw0,
                                                      const float* __restrict__ cb0,
                                                      const float* __restrict__ lw0,
                                                      const float* __restrict__ lb0,
                                                      const float* __restrict__ cwr0,
                                                      const float* __restrict__ cb1,
                                                      const float* __restrict__ lw1,
                                                      const float* __restrict__ lb1,
                                                      float* __restrict__ h2) {
    __shared__ float accr[BNODES * 16];   // 16 KB
    __shared__ float ssum[BNODES];
    __shared__ float sd[BNODES], sb0[BNODES];
    __shared__ float sLW0[256], sCWR[256], sLW1[256];
    __shared__ float scw0[16], scb0[16], slb0[16], scb1[16], slb1[16];
    int u = blockIdx.x, t = threadIdx.x;
    if (t < 256) {
        sLW0[t] = lw0[t];
        sCWR[t] = cwr0[t];
        sLW1[t] = lw1[t];
        int n = u * BNODES + t;
        sd[t] = (n < N_NODES) ? dinv[n] : 0.f;
        sb0[t] = (n < N_NODES) ? base0[n] : 0.f;
        ssum[t] = 0.f;
    }
    if (t < 16) {
        scw0[t] = cw0[t]; scb0[t] = cb0[t]; slb0[t] = lb0[t];
        scb1[t] = cb1[t]; slb1[t] = lb1[t];
    }
    for (int i = t; i < BNODES * 16; i += 512) accr[i] = 0.f;
    __syncthreads();
    int b0 = bstart[u], b1 = bstart[u + 1];
    int j = t & 15, es = t >> 4;   // 32 edge slots x 16 feature lanes
    for (int i = b0 + (es << 2); i < b1; i += 128) {
        u64 ent[4];
        float bs[4];
#pragma unroll
        for (int k = 0; k < 4; ++k)
            if (i + k < b1) ent[k] = bucketed[i + k];
#pragma unroll
        for (int k = 0; k < 4; ++k)
            if (i + k < b1) bs[k] = base0[(int)(ent[k] & 0x3ffffu)];
#pragma unroll
        for (int k = 0; k < 4; ++k)
            if (i + k < b1) {
                int dl = (int)((ent[k] >> 18) & 255u);
                float w = __uint_as_float((unsigned)(ent[k] >> 32));
                float r = fmaxf(bs[k] * scw0[j] + scb0[j], 0.f);
                atomicAdd(&accr[dl * 16 + j], w * r);
                if (j == 0) atomicAdd(&ssum[dl], w);
            }
    }
    __syncthreads();
    int bl = (t & 63) & ~15;
    for (int l0 = 0; l0 < BNODES; l0 += 32) {
        int l = l0 + (t >> 4);
        int n = u * BNODES + l;
        float dn = sd[l];
        float rself = fmaxf(sb0[l] * scw0[j] + scb0[j], 0.f);
        float q = accr[l * 16 + j] + dn * dn * rself;
        float c = ssum[l] + dn * dn;
        float v1 = c * slb0[j];
#pragma unroll
        for (int k = 0; k < 16; ++k) v1 += __shfl(q, bl + k, 64) * sLW0[k * 16 + j];
        float v2 = scb1[j];
#pragma unroll
        for (int k = 0; k < 16; ++k) v2 += __shfl(v1, bl + k, 64) * sCWR[k * 16 + j];
        float a = fmaxf(v2, 0.f);
        float o = slb1[j];
#pragma unroll
        for (int k = 0; k < 16; ++k) o += __shfl(a, bl + k, 64) * sLW1[k * 16 + j];
        if (n < N_NODES) h2[(size_t)n * 16 + j] = o;
    }
}

// layer 2 aggregation: one-shot massive-TLP (round-1 structure), raw[d] += w*h2[s]
__global__ __launch_bounds__(256) void agg2_kernel(const u64* __restrict__ bucketed,
                                                   const int* __restrict__ bstart,
                                                   const float* __restrict__ h2,
                                                   float* __restrict__ raw) {
    int u = blockIdx.x;
    int b0 = bstart[u], b1 = bstart[u + 1];
    int t = threadIdx.x;
    int grp = t >> 4, j = t & 15;
    for (int i = b0 + blockIdx.y * 16 + grp; i < b1; i += YCH * 16) {
        u64 ent = bucketed[i];
        int s = (int)(ent & 0x3ffffu);
        int dl = (int)((ent >> 18) & 255u);
        float w = __uint_as_float((unsigned)(ent >> 32));
        float g = h2[(size_t)s * 16 + j];
        atomicAdd(&raw[((size_t)(u * BNODES + dl)) * 16 + j], w * g);
    }
}

// layer 2 epilogue: h3 = relu((raw + dn^2*h2)@cwr1 + cb2) @ lw2 + lb2
__global__ __launch_bounds__(256) void epi2_kernel(const float* __restrict__ raw,
                                                   const float* __restrict__ h2,
                                                   const float* __restrict__ dinv,
                                                   const float* __restrict__ cwr1,
                                                   const float* __restrict__ cb2,
                                                   const float* __restrict__ lw2,
                                                   const float* __restrict__ lb2,
                                                   float* __restrict__ h3) {
    __shared__ float sW1[256], sW2[256], scb[16], slb[16];
    int t = threadIdx.x;
    sW1[t] = cwr1[t];
    sW2[t] = lw2[t];
    if (t < 16) { scb[t] = cb2[t]; slb[t] = lb2[t]; }
    __syncthreads();
    int nl = t >> 4, j = t & 15;
    int n = blockIdx.x * 16 + nl;            // grid 12500 x 16 = 200000 exactly
    float dn = dinv[n];
    float z = raw[(size_t)n * 16 + j] + dn * dn * h2[(size_t)n * 16 + j];
    int bl = (t & 63) & ~15;
    float v = scb[j];
#pragma unroll
    for (int k = 0; k < 16; ++k) v += __shfl(z, bl + k, 64) * sW1[k * 16 + j];
    float a = fmaxf(v, 0.f);
    float o = slb[j];
#pragma unroll
    for (int k = 0; k < 16; ++k) o += __shfl(a, bl + k, 64) * sW2[k * 16 + j];
    h3[(size_t)n * 16 + j] = o;
}

// segmented pooling over sorted batch
#define POOL_RUN 32
__global__ __launch_bounds__(256) void pool_kernel(const float* __restrict__ h,
                                                   const int* __restrict__ batch,
                                                   float* __restrict__ num,
                                                   float* __restrict__ den) {
    int t = threadIdx.x;
    int tg = t >> 4, j = t & 15;
    int n_start = blockIdx.x * (16 * POOL_RUN) + tg * POOL_RUN;
    float accn = 0.f, accd = 0.f;
    int cur = -1;
    for (int k = 0; k < POOL_RUN; ++k) {
        int n = n_start + k;
        if (n >= N_NODES) break;
        int g = batch[n];
        if (g != cur) {
            if (cur >= 0) {
                atomicAdd(&num[cur * HD + j], accn);
                atomicAdd(&den[cur * HD + j], accd);
            }
            cur = g;
            accn = 0.f;
            accd = 0.f;
        }
        float v = h[(size_t)n * HD + j];
        float s = expf(ALPHA_ * v);
        accn += v * s;
        accd += s;
    }
    if (cur >= 0) {
        atomicAdd(&num[cur * HD + j], accn);
        atomicAdd(&den[cur * HD + j], accd);
    }
}

__global__ __launch_bounds__(64) void final_kernel(const float* __restrict__ num,
                                                   const float* __restrict__ den,
                                                   const float* __restrict__ w1,
                                                   const float* __restrict__ b1,
                                                   const float* __restrict__ w2,
                                                   const float* __restrict__ b2,
                                                   const float* __restrict__ w3,
                                                   const float* __restrict__ b3,
                                                   float* __restrict__ out) {
    int g = blockIdx.x * blockDim.x + threadIdx.x;
    if (g >= N_GRAPHS) return;
    float p[16];
#pragma unroll
    for (int j = 0; j < 16; ++j) p[j] = num[g * HD + j] / den[g * HD + j];
    float t1[16];
#pragma unroll
    for (int j = 0; j < 16; ++j) {
        float acc = b1[j];
#pragma unroll
        for (int k = 0; k < 16; ++k) acc += p[k] * w1[k * 16 + j];
        t1[j] = fmaxf(acc, 0.f);
    }
    float t2[16];
#pragma unroll
    for (int j = 0; j < 16; ++j) {
        float acc = b2[j];
#pragma unroll
        for (int k = 0; k < 16; ++k) acc += t1[k] * w2[k * 16 + j];
        t2[j] = fmaxf(acc, 0.f);
    }
    float o = b3[0];
#pragma unroll
    for (int k = 0; k < 16; ++k) o += t2[k] * w3[k];
    out[g] = o;
}

extern "C" void kernel_launch(void* const* d_in, const int* in_sizes, int n_in,
                              void* d_out, int out_size, void* d_ws, size_t ws_size,
                              hipStream_t stream) {
    const float* x   = (const float*)d_in[0];
    const int*   ei  = (const int*)d_in[1];
    const int*   src = ei;
    const int*   dst = ei + N_EDGES;
    const int*   batch = (const int*)d_in[2];
    const float* ea  = (const float*)d_in[3];
    const float* cw0 = (const float*)d_in[4];
    const float* cwr = (const float*)d_in[5];
    const float* cb  = (const float*)d_in[6];
    const float* lw  = (const float*)d_in[7];
    const float* lb  = (const float*)d_in[8];
    const float* w1  = (const float*)d_in[9];
    const float* b1  = (const float*)d_in[10];
    const float* w2  = (const float*)d_in[11];
    const float* b2  = (const float*)d_in[12];
    const float* w3  = (const float*)d_in[13];
    const float* b3  = (const float*)d_in[14];
    float* out = (float*)d_out;

    // workspace layout (4-byte units); dx / bucketed at even 4-byte offsets
    float* ws      = (float*)d_ws;
    float* dinv    = ws;                                   // 200000
    float* base0   = ws + 200000;                          // 200000
    int*   blkhist = (int*)(ws + 400000);                  // 611524
    int*   bstart  = blkhist + 611524;                     // 783 (pad 784)
    float* num     = (float*)(bstart + 784);               // 16384
    float* den     = num + 16384;                          // 16384
    float2* dx     = (float2*)(den + 16384);               // 200000 float2 (offset 1045076, even)
    u64* bucketed  = (u64*)((float*)dx + 400000);          // E u64 (offset 1445076, even)
    float* h2      = (float*)(bucketed + N_EDGES);         // N*16
    float* raw     = h2 + (size_t)N_NODES * HD;            // N*16
    float* h3      = raw + (size_t)N_NODES * HD;           // N*16

    hipMemsetAsync(num, 0, (size_t)2 * N_GRAPHS * HD * sizeof(float), stream);
    hipMemsetAsync(raw, 0, (size_t)N_NODES * HD * sizeof(float), stream);

    // bucket sort by dst>>8
    hist_kernel<<<NBLKA, 256, 0, stream>>>(dst, blkhist);
    scanA_kernel<<<NBUCK, 256, 0, stream>>>(blkhist, bstart);
    scanB_kernel<<<1, 256, 0, stream>>>(bstart);
    scatter_kernel<<<NBLKA, 256, 0, stream>>>(src, dst, ea, blkhist, bstart, bucketed);

    // degree -> dinv + dx
    dinvB_kernel<<<NBUCK, 256, 0, stream>>>(bucketed, bstart, x, dinv, dx);

    // layer 0: scalar agg + weight rewrite -> base0
    agg0_kernel<<<NBUCK, 512, 0, stream>>>(bucketed, bstart, dx, base0);
    // layer 1: scalar-gather recompute; full fused epilogue -> h2
    agg1_kernel<<<NBUCK, 512, 0, stream>>>(bucketed, bstart, base0, dinv,
                                           cw0, cb, lw, lb,
                                           cwr, cb + 16, lw + 256, lb + 16, h2);
    // layer 2: one-shot TLP gather+atomics -> raw, then epilogue -> h3
    agg2_kernel<<<dim3(NBUCK, YCH), 256, 0, stream>>>(bucketed, bstart, h2, raw);
    epi2_kernel<<<12500, 256, 0, stream>>>(raw, h2, dinv, cwr + 256,
                                           cb + 32, lw + 512, lb + 32, h3);

    pool_kernel<<<(N_NODES + 16 * POOL_RUN - 1) / (16 * POOL_RUN), 256, 0, stream>>>(h3, batch, num, den);
    final_kernel<<<(N_GRAPHS + 63) / 64, 64, 0, stream>>>(num, den, w1, b1, w2, b2, w3, b3, out);
}

// Round 6
// 556.624 us; speedup vs baseline: 1.8187x; 1.8187x over previous
//
#include <hip/hip_runtime.h>

#define N_NODES 200000
#define N_EDGES 3200000
#define N_GRAPHS 1024
#define HD 16
#define ALPHA_ 0.2f

#define BNODES 256                 // nodes per bucket (dst >> 8)
#define NBUCK 782                  // ceil(N_NODES/256)
#define CHUNKA 1024                // edges per pass-A block
#define NBLKA 3125                 // ceil(N_EDGES/CHUNKA)
#define PERA 13                    // ceil(NBLKA/256)

typedef unsigned long long u64;

// ---------- radix pass 1: bucket by dst>>8 (int LDS atomics only) ----------
__global__ __launch_bounds__(256) void hist_kernel(const int* __restrict__ dst,
                                                   int* __restrict__ blkhist) {
    __shared__ int hist[NBUCK];
    int t = threadIdx.x;
    for (int i = t; i < NBUCK; i += 256) hist[i] = 0;
    __syncthreads();
    int e0 = blockIdx.x * CHUNKA;
    int e1 = min(e0 + CHUNKA, N_EDGES);
    for (int e = e0 + t; e < e1; e += 256)
        atomicAdd(&hist[dst[e] >> 8], 1);
    __syncthreads();
    int* out = blkhist + (size_t)blockIdx.x * NBUCK;
    for (int i = t; i < NBUCK; i += 256) out[i] = hist[i];
}

// column-wise exclusive scan across NBLKA blocks; totals -> bstart
__global__ __launch_bounds__(256) void scanA_kernel(int* __restrict__ blkhist,
                                                    int* __restrict__ bstart) {
    __shared__ int s[256];
    int u = blockIdx.x, t = threadIdx.x;
    int v[PERA];
    int sum = 0;
#pragma unroll
    for (int i = 0; i < PERA; ++i) {
        int j = t * PERA + i;
        v[i] = (j < NBLKA) ? blkhist[(size_t)j * NBUCK + u] : 0;
        sum += v[i];
    }
    s[t] = sum;
    __syncthreads();
    for (int off = 1; off < 256; off <<= 1) {
        int x = (t >= off) ? s[t - off] : 0;
        __syncthreads();
        s[t] += x;
        __syncthreads();
    }
    int run = s[t] - sum;
#pragma unroll
    for (int i = 0; i < PERA; ++i) {
        int j = t * PERA + i;
        if (j < NBLKA) blkhist[(size_t)j * NBUCK + u] = run;
        run += v[i];
    }
    if (t == 255) bstart[u] = s[255];
}

// exclusive scan over bucket totals (single block)
__global__ __launch_bounds__(256) void scanB_kernel(int* __restrict__ bstart) {
    __shared__ int s[256];
    int t = threadIdx.x;
    int v[4];
    int sum = 0;
#pragma unroll
    for (int i = 0; i < 4; ++i) {
        int j = t * 4 + i;
        v[i] = (j < NBUCK) ? bstart[j] : 0;
        sum += v[i];
    }
    s[t] = sum;
    __syncthreads();
    for (int off = 1; off < 256; off <<= 1) {
        int x = (t >= off) ? s[t - off] : 0;
        __syncthreads();
        s[t] += x;
        __syncthreads();
    }
    int run = s[t] - sum;
#pragma unroll
    for (int i = 0; i < 4; ++i) {
        int j = t * 4 + i;
        if (j < NBUCK) bstart[j] = run;
        run += v[i];
    }
    if (t == 255) bstart[NBUCK] = s[255];
}

// entry = (ea:32 | dlow:8 | src:18)
__global__ __launch_bounds__(256) void scatter_kernel(const int* __restrict__ src,
                                                      const int* __restrict__ dst,
                                                      const float* __restrict__ ea,
                                                      const int* __restrict__ blkhist,
                                                      const int* __restrict__ bstart,
                                                      u64* __restrict__ bucketed) {
    __shared__ int cursor[NBUCK];
    int t = threadIdx.x;
    const int* bo = blkhist + (size_t)blockIdx.x * NBUCK;
    for (int i = t; i < NBUCK; i += 256) cursor[i] = bstart[i] + bo[i];
    __syncthreads();
    int e0 = blockIdx.x * CHUNKA;
    int e1 = min(e0 + CHUNKA, N_EDGES);
    for (int e = e0 + t; e < e1; e += 256) {
        int d = dst[e];
        int u = d >> 8;
        int pos = atomicAdd(&cursor[u], 1);   // int LDS atomic (native, fast)
        u64 ent = ((u64)__float_as_uint(ea[e]) << 32)
                | (unsigned)(src[e] | ((d & 255) << 18));
        bucketed[pos] = ent;
    }
}

// radix pass 2: in-bucket counting sort by dlow (int LDS atomics only);
// emits fully-sorted edge array + per-node CSR offsets
__global__ __launch_bounds__(256) void sortd_kernel(const u64* __restrict__ bucketed,
                                                    const int* __restrict__ bstart,
                                                    u64* __restrict__ sorted,
                                                    int* __restrict__ nodeoff) {
    __shared__ int hist[256];
    __shared__ int s[256];
    __shared__ int cur[256];
    int u = blockIdx.x, t = threadIdx.x;
    hist[t] = 0;
    __syncthreads();
    int b0 = bstart[u], b1 = bstart[u + 1];
    for (int i = b0 + t; i < b1; i += 256)
        atomicAdd(&hist[(int)((bucketed[i] >> 18) & 255u)], 1);
    __syncthreads();
    int c = hist[t];
    s[t] = c;
    __syncthreads();
    for (int off = 1; off < 256; off <<= 1) {
        int v = (t >= off) ? s[t - off] : 0;
        __syncthreads();
        s[t] += v;
        __syncthreads();
    }
    int loc = s[t] - c;   // exclusive
    cur[t] = b0 + loc;
    int n = u * BNODES + t;
    if (n < N_NODES) nodeoff[n] = b0 + loc;
    __syncthreads();
    for (int i = b0 + t; i < b1; i += 256) {
        u64 ent = bucketed[i];
        int pos = atomicAdd(&cur[(int)((ent >> 18) & 255u)], 1);
        sorted[pos] = ent;
    }
}

// per-node serial: weighted degree -> dinv, dx = {dinv, dinv*x}
__global__ __launch_bounds__(256) void dinvC_kernel(const u64* __restrict__ sorted,
                                                    const int* __restrict__ nodeoff,
                                                    const float* __restrict__ x,
                                                    float* __restrict__ dinv,
                                                    float2* __restrict__ dx) {
    int n = blockIdx.x * 256 + threadIdx.x;
    if (n >= N_NODES) return;
    int e0 = nodeoff[n];
    int e1 = (n < N_NODES - 1) ? nodeoff[n + 1] : N_EDGES;
    float sum = 0.f;
    for (int i = e0; i < e1; ++i)
        sum += __uint_as_float((unsigned)(sorted[i] >> 32));
    float dn = rsqrtf(sum + 1.0f);
    dinv[n] = dn;
    dx[n] = make_float2(dn, dn * x[n]);
}

// layer 0 per-node serial: rewrite ea->w in place, base0 = sum w*x[s] + dn^2*x[n],
// s1 = sum w + dn^2  (layer-independent, reused by agg1)
__global__ __launch_bounds__(256) void agg0_kernel(u64* __restrict__ sorted,
                                                   const int* __restrict__ nodeoff,
                                                   const float2* __restrict__ dx,
                                                   float* __restrict__ base0,
                                                   float* __restrict__ s1) {
    int n = blockIdx.x * 256 + threadIdx.x;
    if (n >= N_NODES) return;
    int e0 = nodeoff[n];
    int e1 = (n < N_NODES - 1) ? nodeoff[n + 1] : N_EDGES;
    float2 d2 = dx[n];
    float dn = d2.x;
    float acc = 0.f, wsum = 0.f;
    for (int i = e0; i < e1; ++i) {
        u64 ent = sorted[i];
        float2 g = dx[(int)(ent & 0x3ffffu)];
        float wd = __uint_as_float((unsigned)(ent >> 32)) * dn;  // ea * dinv[d]
        float w = wd * g.x;
        sorted[i] = ((u64)__float_as_uint(w) << 32) | (unsigned)(ent & 0x03ffffffu);
        acc += wd * g.y;   // = w * x[s]
        wsum += w;
    }
    base0[n] = acc + dn * d2.y;       // + dn^2 * x[n]
    s1[n] = wsum + dn * dn;
}

// layer 1: 16 lanes per node; gather scalar base0[s] (L2-resident), no atomics.
// h2 = relu((q@lw0 + s1*lb0)@cwr0 + cb1) @ lw1 + lb1
__global__ __launch_bounds__(256) void agg1_kernel(const u64* __restrict__ sorted,
                                                   const int* __restrict__ nodeoff,
                                                   const float* __restrict__ base0,
                                                   const float* __restrict__ s1,
                                                   const float* __restrict__ dinv,
                                                   const float* __restrict__ cw0,
                                                   const float* __restrict__ cb0,
                                                   const float* __restrict__ lw0,
                                                   const float* __restrict__ lb0,
                                                   const float* __restrict__ cwr0,
                                                   const float* __restrict__ cb1,
                                                   const float* __restrict__ lw1,
                                                   const float* __restrict__ lb1,
                                                   float* __restrict__ h2) {
    __shared__ float sLW0[256], sCWR[256], sLW1[256];
    __shared__ float scw0[16], scb0[16], slb0[16], scb1[16], slb1[16];
    int t = threadIdx.x;
    sLW0[t] = lw0[t];
    sCWR[t] = cwr0[t];
    sLW1[t] = lw1[t];
    if (t < 16) {
        scw0[t] = cw0[t]; scb0[t] = cb0[t]; slb0[t] = lb0[t];
        scb1[t] = cb1[t]; slb1[t] = lb1[t];
    }
    __syncthreads();
    int nl = t >> 4, j = t & 15;
    int n = blockIdx.x * 16 + nl;            // 12500 * 16 = 200000 exactly
    int e0 = nodeoff[n];
    int e1 = (n < N_NODES - 1) ? nodeoff[n + 1] : N_EDGES;
    float cwj = scw0[j], cbj = scb0[j];
    float q = 0.f;
    for (int i = e0; i < e1; ++i) {
        u64 ent = sorted[i];                         // broadcast across 16 lanes
        float bs = base0[(int)(ent & 0x3ffffu)];     // broadcast 4B gather
        float w = __uint_as_float((unsigned)(ent >> 32));
        q += w * fmaxf(bs * cwj + cbj, 0.f);
    }
    float dn = dinv[n];
    q += dn * dn * fmaxf(base0[n] * cwj + cbj, 0.f);
    float c = s1[n];
    int bl = (t & 63) & ~15;
    float v1 = c * slb0[j];
#pragma unroll
    for (int k = 0; k < 16; ++k) v1 += __shfl(q, bl + k, 64) * sLW0[k * 16 + j];
    float v2 = scb1[j];
#pragma unroll
    for (int k = 0; k < 16; ++k) v2 += __shfl(v1, bl + k, 64) * sCWR[k * 16 + j];
    float a = fmaxf(v2, 0.f);
    float o = slb1[j];
#pragma unroll
    for (int k = 0; k < 16; ++k) o += __shfl(a, bl + k, 64) * sLW1[k * 16 + j];
    h2[(size_t)n * 16 + j] = o;
}

// layer 2: 16 lanes per node; coalesced 64B gather h2[s][:]; fused epilogue -> h3
__global__ __launch_bounds__(256) void agg2_kernel(const u64* __restrict__ sorted,
                                                   const int* __restrict__ nodeoff,
                                                   const float* __restrict__ h2,
                                                   const float* __restrict__ dinv,
                                                   const float* __restrict__ cwr1,
                                                   const float* __restrict__ cb2,
                                                   const float* __restrict__ lw2,
                                                   const float* __restrict__ lb2,
                                                   float* __restrict__ h3) {
    __shared__ float sW1[256], sW2[256], scb[16], slb[16];
    int t = threadIdx.x;
    sW1[t] = cwr1[t];
    sW2[t] = lw2[t];
    if (t < 16) { scb[t] = cb2[t]; slb[t] = lb2[t]; }
    __syncthreads();
    int nl = t >> 4, j = t & 15;
    int n = blockIdx.x * 16 + nl;
    int e0 = nodeoff[n];
    int e1 = (n < N_NODES - 1) ? nodeoff[n + 1] : N_EDGES;
    float q = 0.f;
    for (int i = e0; i < e1; ++i) {
        u64 ent = sorted[i];                         // broadcast across 16 lanes
        float g = h2[(size_t)(ent & 0x3ffffu) * 16 + j];   // one 64B line / edge
        float w = __uint_as_float((unsigned)(ent >> 32));
        q += w * g;
    }
    float dn = dinv[n];
    float z = q + dn * dn * h2[(size_t)n * 16 + j];
    int bl = (t & 63) & ~15;
    float v = scb[j];
#pragma unroll
    for (int k = 0; k < 16; ++k) v += __shfl(z, bl + k, 64) * sW1[k * 16 + j];
    float a = fmaxf(v, 0.f);
    float o = slb[j];
#pragma unroll
    for (int k = 0; k < 16; ++k) o += __shfl(a, bl + k, 64) * sW2[k * 16 + j];
    h3[(size_t)n * 16 + j] = o;
}

// segmented pooling over sorted batch (few global fp atomics; ~116k total)
#define POOL_RUN 32
__global__ __launch_bounds__(256) void pool_kernel(const float* __restrict__ h,
                                                   const int* __restrict__ batch,
                                                   float* __restrict__ num,
                                                   float* __restrict__ den) {
    int t = threadIdx.x;
    int tg = t >> 4, j = t & 15;
    int n_start = blockIdx.x * (16 * POOL_RUN) + tg * POOL_RUN;
    float accn = 0.f, accd = 0.f;
    int cur = -1;
    for (int k = 0; k < POOL_RUN; ++k) {
        int n = n_start + k;
        if (n >= N_NODES) break;
        int g = batch[n];
        if (g != cur) {
            if (cur >= 0) {
                atomicAdd(&num[cur * HD + j], accn);
                atomicAdd(&den[cur * HD + j], accd);
            }
            cur = g;
            accn = 0.f;
            accd = 0.f;
        }
        float v = h[(size_t)n * HD + j];
        float s = expf(ALPHA_ * v);
        accn += v * s;
        accd += s;
    }
    if (cur >= 0) {
        atomicAdd(&num[cur * HD + j], accn);
        atomicAdd(&den[cur * HD + j], accd);
    }
}

__global__ __launch_bounds__(64) void final_kernel(const float* __restrict__ num,
                                                   const float* __restrict__ den,
                                                   const float* __restrict__ w1,
                                                   const float* __restrict__ b1,
                                                   const float* __restrict__ w2,
                                                   const float* __restrict__ b2,
                                                   const float* __restrict__ w3,
                                                   const float* __restrict__ b3,
                                                   float* __restrict__ out) {
    int g = blockIdx.x * blockDim.x + threadIdx.x;
    if (g >= N_GRAPHS) return;
    float p[16];
#pragma unroll
    for (int j = 0; j < 16; ++j) p[j] = num[g * HD + j] / den[g * HD + j];
    float t1[16];
#pragma unroll
    for (int j = 0; j < 16; ++j) {
        float acc = b1[j];
#pragma unroll
        for (int k = 0; k < 16; ++k) acc += p[k] * w1[k * 16 + j];
        t1[j] = fmaxf(acc, 0.f);
    }
    float t2[16];
#pragma unroll
    for (int j = 0; j < 16; ++j) {
        float acc = b2[j];
#pragma unroll
        for (int k = 0; k < 16; ++k) acc += t1[k] * w2[k * 16 + j];
        t2[j] = fmaxf(acc, 0.f);
    }
    float o = b3[0];
#pragma unroll
    for (int k = 0; k < 16; ++k) o += t2[k] * w3[k];
    out[g] = o;
}

extern "C" void kernel_launch(void* const* d_in, const int* in_sizes, int n_in,
                              void* d_out, int out_size, void* d_ws, size_t ws_size,
                              hipStream_t stream) {
    const float* x   = (const float*)d_in[0];
    const int*   ei  = (const int*)d_in[1];
    const int*   src = ei;
    const int*   dst = ei + N_EDGES;
    const int*   batch = (const int*)d_in[2];
    const float* ea  = (const float*)d_in[3];
    const float* cw0 = (const float*)d_in[4];
    const float* cwr = (const float*)d_in[5];
    const float* cb  = (const float*)d_in[6];
    const float* lw  = (const float*)d_in[7];
    const float* lb  = (const float*)d_in[8];
    const float* w1  = (const float*)d_in[9];
    const float* b1  = (const float*)d_in[10];
    const float* w2  = (const float*)d_in[11];
    const float* b2  = (const float*)d_in[12];
    const float* w3  = (const float*)d_in[13];
    const float* b3  = (const float*)d_in[14];
    float* out = (float*)d_out;

    // workspace layout (4-byte units)
    float* ws      = (float*)d_ws;
    float* dinv    = ws;                                   // 200000
    float* base0   = ws + 200000;                          // 200000
    float* s1      = ws + 400000;                          // 200000
    int*   blkhist = (int*)(ws + 600000);                  // NBLKA*NBUCK = 2443750
    int*   bstart  = blkhist + 2443750;                    // 783 (pad 784)
    int*   nodeoff = bstart + 784;                         // 200000 (pad 200010)
    float* num     = (float*)(nodeoff + 200010);           // 16384
    float* den     = num + 16384;                          // 16384
    float2* dx     = (float2*)(den + 16384);               // 200000 float2 (even off)
    u64* bucketed  = (u64*)((float*)dx + 400000);          // E u64
    u64* sorted    = bucketed + N_EDGES;                   // E u64
    float* h2      = (float*)bucketed;                     // alias: free after sortd
    float* h3      = h2 + (size_t)N_NODES * HD;            // alias (bucketed region)

    hipMemsetAsync(num, 0, (size_t)2 * N_GRAPHS * HD * sizeof(float), stream);

    // full sort by dst: radix pass 1 (bucket dst>>8), pass 2 (in-bucket dlow)
    hist_kernel<<<NBLKA, 256, 0, stream>>>(dst, blkhist);
    scanA_kernel<<<NBUCK, 256, 0, stream>>>(blkhist, bstart);
    scanB_kernel<<<1, 256, 0, stream>>>(bstart);
    scatter_kernel<<<NBLKA, 256, 0, stream>>>(src, dst, ea, blkhist, bstart, bucketed);
    sortd_kernel<<<NBUCK, 256, 0, stream>>>(bucketed, bstart, sorted, nodeoff);

    // per-node serial (atomic-free): degree, layer-0 scalar agg + weight rewrite
    dinvC_kernel<<<NBUCK, 256, 0, stream>>>(sorted, nodeoff, x, dinv, dx);
    agg0_kernel<<<NBUCK, 256, 0, stream>>>(sorted, nodeoff, dx, base0, s1);

    // layer 1 (scalar-gather recompute) -> h2 ; layer 2 (64B-line gather) -> h3
    agg1_kernel<<<12500, 256, 0, stream>>>(sorted, nodeoff, base0, s1, dinv,
                                           cw0, cb, lw, lb,
                                           cwr, cb + 16, lw + 256, lb + 16, h2);
    agg2_kernel<<<12500, 256, 0, stream>>>(sorted, nodeoff, h2, dinv,
                                           cwr + 256, cb + 32, lw + 512, lb + 32, h3);

    pool_kernel<<<(N_NODES + 16 * POOL_RUN - 1) / (16 * POOL_RUN), 256, 0, stream>>>(h3, batch, num, den);
    final_kernel<<<(N_GRAPHS + 63) / 64, 64, 0, stream>>>(num, den, w1, b1, w2, b2, w3, b3, out);
}

// Round 7
// 463.376 us; speedup vs baseline: 2.1847x; 1.2012x over previous
//
#include <hip/hip_runtime.h>

#define N_NODES 200000
#define N_EDGES 3200000
#define N_GRAPHS 1024
#define HD 16
#define ALPHA_ 0.2f

#define BNODES 256                 // nodes per bucket (dst >> 8)
#define NBUCK 782                  // ceil(N_NODES/256)
#define CHUNKA 1024                // edges per pass-A block
#define NBLKA 3125                 // ceil(N_EDGES/CHUNKA)
#define PERA 13                    // ceil(NBLKA/256)

typedef unsigned long long u64;

// ---------- radix pass 1: bucket by dst>>8 (int LDS atomics only) ----------
__global__ __launch_bounds__(256) void hist_kernel(const int* __restrict__ dst,
                                                   int* __restrict__ blkhist) {
    __shared__ int hist[NBUCK];
    int t = threadIdx.x;
    for (int i = t; i < NBUCK; i += 256) hist[i] = 0;
    __syncthreads();
    int e0 = blockIdx.x * CHUNKA;
    int e1 = min(e0 + CHUNKA, N_EDGES);
    for (int e = e0 + t; e < e1; e += 256)
        atomicAdd(&hist[dst[e] >> 8], 1);
    __syncthreads();
    int* out = blkhist + (size_t)blockIdx.x * NBUCK;
    for (int i = t; i < NBUCK; i += 256) out[i] = hist[i];
}

// column-wise exclusive scan across NBLKA blocks; totals -> bstart
__global__ __launch_bounds__(256) void scanA_kernel(int* __restrict__ blkhist,
                                                    int* __restrict__ bstart) {
    __shared__ int s[256];
    int u = blockIdx.x, t = threadIdx.x;
    int v[PERA];
    int sum = 0;
#pragma unroll
    for (int i = 0; i < PERA; ++i) {
        int j = t * PERA + i;
        v[i] = (j < NBLKA) ? blkhist[(size_t)j * NBUCK + u] : 0;
        sum += v[i];
    }
    s[t] = sum;
    __syncthreads();
    for (int off = 1; off < 256; off <<= 1) {
        int x = (t >= off) ? s[t - off] : 0;
        __syncthreads();
        s[t] += x;
        __syncthreads();
    }
    int run = s[t] - sum;
#pragma unroll
    for (int i = 0; i < PERA; ++i) {
        int j = t * PERA + i;
        if (j < NBLKA) blkhist[(size_t)j * NBUCK + u] = run;
        run += v[i];
    }
    if (t == 255) bstart[u] = s[255];
}

// exclusive scan over bucket totals (single block)
__global__ __launch_bounds__(256) void scanB_kernel(int* __restrict__ bstart) {
    __shared__ int s[256];
    int t = threadIdx.x;
    int v[4];
    int sum = 0;
#pragma unroll
    for (int i = 0; i < 4; ++i) {
        int j = t * 4 + i;
        v[i] = (j < NBUCK) ? bstart[j] : 0;
        sum += v[i];
    }
    s[t] = sum;
    __syncthreads();
    for (int off = 1; off < 256; off <<= 1) {
        int x = (t >= off) ? s[t - off] : 0;
        __syncthreads();
        s[t] += x;
        __syncthreads();
    }
    int run = s[t] - sum;
#pragma unroll
    for (int i = 0; i < 4; ++i) {
        int j = t * 4 + i;
        if (j < NBUCK) bstart[j] = run;
        run += v[i];
    }
    if (t == 255) bstart[NBUCK] = s[255];
}

// entry = (ea:32 | dlow:8 | src:18) — ea stays raw forever (dinv[d] factored out)
__global__ __launch_bounds__(256) void scatter_kernel(const int* __restrict__ src,
                                                      const int* __restrict__ dst,
                                                      const float* __restrict__ ea,
                                                      const int* __restrict__ blkhist,
                                                      const int* __restrict__ bstart,
                                                      u64* __restrict__ bucketed) {
    __shared__ int cursor[NBUCK];
    int t = threadIdx.x;
    const int* bo = blkhist + (size_t)blockIdx.x * NBUCK;
    for (int i = t; i < NBUCK; i += 256) cursor[i] = bstart[i] + bo[i];
    __syncthreads();
    int e0 = blockIdx.x * CHUNKA;
    int e1 = min(e0 + CHUNKA, N_EDGES);
    for (int e = e0 + t; e < e1; e += 256) {
        int d = dst[e];
        int u = d >> 8;
        int pos = atomicAdd(&cursor[u], 1);   // int LDS atomic (native, fast)
        u64 ent = ((u64)__float_as_uint(ea[e]) << 32)
                | (unsigned)(src[e] | ((d & 255) << 18));
        bucketed[pos] = ent;
    }
}

// radix pass 2: in-bucket counting sort by dlow (int LDS atomics) + fused
// per-node weighted degree -> dinv, dx = {dinv, dinv*x}
__global__ __launch_bounds__(256) void sortd_kernel(const u64* __restrict__ bucketed,
                                                    const int* __restrict__ bstart,
                                                    const float* __restrict__ x,
                                                    u64* __restrict__ sorted,
                                                    int* __restrict__ nodeoff,
                                                    float* __restrict__ dinv,
                                                    float2* __restrict__ dx) {
    __shared__ int hist[256];
    __shared__ int s[256];
    __shared__ int cur[256];
    int u = blockIdx.x, t = threadIdx.x;
    hist[t] = 0;
    __syncthreads();
    int b0 = bstart[u], b1 = bstart[u + 1];
    for (int i = b0 + t; i < b1; i += 256)
        atomicAdd(&hist[(int)((bucketed[i] >> 18) & 255u)], 1);
    __syncthreads();
    int c = hist[t];
    s[t] = c;
    __syncthreads();
    for (int off = 1; off < 256; off <<= 1) {
        int v = (t >= off) ? s[t - off] : 0;
        __syncthreads();
        s[t] += v;
        __syncthreads();
    }
    int loc = s[t] - c;   // exclusive
    cur[t] = b0 + loc;
    int n = u * BNODES + t;
    if (n < N_NODES) nodeoff[n] = b0 + loc;
    __syncthreads();
    for (int i = b0 + t; i < b1; i += 256) {
        u64 ent = bucketed[i];
        int pos = atomicAdd(&cur[(int)((ent >> 18) & 255u)], 1);
        sorted[pos] = ent;
    }
    __syncthreads();
    // per-node serial weighted degree over own contiguous range (L1/L2-hot)
    if (n < N_NODES) {
        float sum = 0.f;
        int e0 = b0 + loc;
        for (int k = 0; k < c; ++k)
            sum += __uint_as_float((unsigned)(sorted[e0 + k] >> 32));
        float dn = rsqrtf(sum + 1.0f);
        dinv[n] = dn;
        dx[n] = make_float2(dn, dn * x[n]);
    }
}

// layer 0 (read-only, unroll-4): base0 = dn*sum(ea*(dinv*x)[s]) + dn^2*x[n]
// s1 = dn*sum(ea*dinv[s]) + dn^2 ; db0[n] = {dinv, base0}
__global__ __launch_bounds__(256) void agg0_kernel(const u64* __restrict__ sorted,
                                                   const int* __restrict__ nodeoff,
                                                   const float2* __restrict__ dx,
                                                   float2* __restrict__ db0,
                                                   float* __restrict__ s1v) {
    int n = blockIdx.x * 256 + threadIdx.x;
    if (n >= N_NODES) return;
    int e0 = nodeoff[n];
    int e1 = (n < N_NODES - 1) ? nodeoff[n + 1] : N_EDGES;
    float2 d2 = dx[n];
    float dn = d2.x;
    float acc = 0.f, wsum = 0.f;
    int i = e0;
    for (; i + 4 <= e1; i += 4) {
        u64 en0 = sorted[i], en1 = sorted[i + 1], en2 = sorted[i + 2], en3 = sorted[i + 3];
        float2 g0 = dx[(int)(en0 & 0x3ffffu)];
        float2 g1 = dx[(int)(en1 & 0x3ffffu)];
        float2 g2 = dx[(int)(en2 & 0x3ffffu)];
        float2 g3 = dx[(int)(en3 & 0x3ffffu)];
        float a0 = __uint_as_float((unsigned)(en0 >> 32));
        float a1 = __uint_as_float((unsigned)(en1 >> 32));
        float a2 = __uint_as_float((unsigned)(en2 >> 32));
        float a3 = __uint_as_float((unsigned)(en3 >> 32));
        acc += a0 * g0.y + a1 * g1.y + a2 * g2.y + a3 * g3.y;
        wsum += a0 * g0.x + a1 * g1.x + a2 * g2.x + a3 * g3.x;
    }
    for (; i < e1; ++i) {
        u64 en = sorted[i];
        float2 g = dx[(int)(en & 0x3ffffu)];
        float a = __uint_as_float((unsigned)(en >> 32));
        acc += a * g.y;
        wsum += a * g.x;
    }
    float base0 = dn * acc + dn * d2.y;     // + dn^2 * x[n]
    db0[n] = make_float2(dn, base0);
    s1v[n] = dn * wsum + dn * dn;
}

// layer 1: 16 lanes/node, unroll-4 float2 gathers of db0[s]; no atomics.
// writes h2hat = dinv * h2
__global__ __launch_bounds__(256) void agg1_kernel(const u64* __restrict__ sorted,
                                                   const int* __restrict__ nodeoff,
                                                   const float2* __restrict__ db0,
                                                   const float* __restrict__ s1v,
                                                   const float* __restrict__ cw0,
                                                   const float* __restrict__ cb0,
                                                   const float* __restrict__ lw0,
                                                   const float* __restrict__ lb0,
                                                   const float* __restrict__ cwr0,
                                                   const float* __restrict__ cb1,
                                                   const float* __restrict__ lw1,
                                                   const float* __restrict__ lb1,
                                                   float* __restrict__ h2hat) {
    __shared__ float sLW0[256], sCWR[256], sLW1[256];
    __shared__ float scw0[16], scb0[16], slb0[16], scb1[16], slb1[16];
    int t = threadIdx.x;
    sLW0[t] = lw0[t];
    sCWR[t] = cwr0[t];
    sLW1[t] = lw1[t];
    if (t < 16) {
        scw0[t] = cw0[t]; scb0[t] = cb0[t]; slb0[t] = lb0[t];
        scb1[t] = cb1[t]; slb1[t] = lb1[t];
    }
    __syncthreads();
    int nl = t >> 4, j = t & 15;
    int n = blockIdx.x * 16 + nl;            // 12500 * 16 = 200000 exactly
    int e0 = nodeoff[n];
    int e1 = (n < N_NODES - 1) ? nodeoff[n + 1] : N_EDGES;
    float cwj = scw0[j], cbj = scb0[j];
    float q = 0.f;
    int i = e0;
    for (; i + 4 <= e1; i += 4) {
        u64 en0 = sorted[i], en1 = sorted[i + 1], en2 = sorted[i + 2], en3 = sorted[i + 3];
        float2 g0 = db0[(int)(en0 & 0x3ffffu)];
        float2 g1 = db0[(int)(en1 & 0x3ffffu)];
        float2 g2 = db0[(int)(en2 & 0x3ffffu)];
        float2 g3 = db0[(int)(en3 & 0x3ffffu)];
        q += __uint_as_float((unsigned)(en0 >> 32)) * (g0.x * fmaxf(g0.y * cwj + cbj, 0.f));
        q += __uint_as_float((unsigned)(en1 >> 32)) * (g1.x * fmaxf(g1.y * cwj + cbj, 0.f));
        q += __uint_as_float((unsigned)(en2 >> 32)) * (g2.x * fmaxf(g2.y * cwj + cbj, 0.f));
        q += __uint_as_float((unsigned)(en3 >> 32)) * (g3.x * fmaxf(g3.y * cwj + cbj, 0.f));
    }
    for (; i < e1; ++i) {
        u64 en = sorted[i];
        float2 g = db0[(int)(en & 0x3ffffu)];
        q += __uint_as_float((unsigned)(en >> 32)) * (g.x * fmaxf(g.y * cwj + cbj, 0.f));
    }
    float2 self = db0[n];
    float dn = self.x;
    q = dn * q + dn * dn * fmaxf(self.y * cwj + cbj, 0.f);
    float c = s1v[n];
    int bl = (t & 63) & ~15;
    float v1 = c * slb0[j];
#pragma unroll
    for (int k = 0; k < 16; ++k) v1 += __shfl(q, bl + k, 64) * sLW0[k * 16 + j];
    float v2 = scb1[j];
#pragma unroll
    for (int k = 0; k < 16; ++k) v2 += __shfl(v1, bl + k, 64) * sCWR[k * 16 + j];
    float a = fmaxf(v2, 0.f);
    float o = slb1[j];
#pragma unroll
    for (int k = 0; k < 16; ++k) o += __shfl(a, bl + k, 64) * sLW1[k * 16 + j];
    h2hat[(size_t)n * 16 + j] = dn * o;     // premultiplied by dinv
}

// layer 2: 16 lanes/node, unroll-4 coalesced 64B line gathers of h2hat[s][:]
__global__ __launch_bounds__(256) void agg2_kernel(const u64* __restrict__ sorted,
                                                   const int* __restrict__ nodeoff,
                                                   const float* __restrict__ h2hat,
                                                   const float* __restrict__ dinv,
                                                   const float* __restrict__ cwr1,
                                                   const float* __restrict__ cb2,
                                                   const float* __restrict__ lw2,
                                                   const float* __restrict__ lb2,
                                                   float* __restrict__ h3) {
    __shared__ float sW1[256], sW2[256], scb[16], slb[16];
    int t = threadIdx.x;
    sW1[t] = cwr1[t];
    sW2[t] = lw2[t];
    if (t < 16) { scb[t] = cb2[t]; slb[t] = lb2[t]; }
    __syncthreads();
    int nl = t >> 4, j = t & 15;
    int n = blockIdx.x * 16 + nl;
    int e0 = nodeoff[n];
    int e1 = (n < N_NODES - 1) ? nodeoff[n + 1] : N_EDGES;
    float q = 0.f;
    int i = e0;
    for (; i + 4 <= e1; i += 4) {
        u64 en0 = sorted[i], en1 = sorted[i + 1], en2 = sorted[i + 2], en3 = sorted[i + 3];
        float g0 = h2hat[(size_t)(en0 & 0x3ffffu) * 16 + j];
        float g1 = h2hat[(size_t)(en1 & 0x3ffffu) * 16 + j];
        float g2 = h2hat[(size_t)(en2 & 0x3ffffu) * 16 + j];
        float g3 = h2hat[(size_t)(en3 & 0x3ffffu) * 16 + j];
        q += __uint_as_float((unsigned)(en0 >> 32)) * g0;
        q += __uint_as_float((unsigned)(en1 >> 32)) * g1;
        q += __uint_as_float((unsigned)(en2 >> 32)) * g2;
        q += __uint_as_float((unsigned)(en3 >> 32)) * g3;
    }
    for (; i < e1; ++i) {
        u64 en = sorted[i];
        q += __uint_as_float((unsigned)(en >> 32)) * h2hat[(size_t)(en & 0x3ffffu) * 16 + j];
    }
    float dn = dinv[n];
    float z = dn * (q + h2hat[(size_t)n * 16 + j]);   // + dn^2 * h2[n]
    int bl = (t & 63) & ~15;
    float v = scb[j];
#pragma unroll
    for (int k = 0; k < 16; ++k) v += __shfl(z, bl + k, 64) * sW1[k * 16 + j];
    float a = fmaxf(v, 0.f);
    float o = slb[j];
#pragma unroll
    for (int k = 0; k < 16; ++k) o += __shfl(a, bl + k, 64) * sW2[k * 16 + j];
    h3[(size_t)n * 16 + j] = o;
}

// segmented pooling over sorted batch (~116k global fp atomics total)
#define POOL_RUN 32
__global__ __launch_bounds__(256) void pool_kernel(const float* __restrict__ h,
                                                   const int* __restrict__ batch,
                                                   float* __restrict__ num,
                                                   float* __restrict__ den) {
    int t = threadIdx.x;
    int tg = t >> 4, j = t & 15;
    int n_start = blockIdx.x * (16 * POOL_RUN) + tg * POOL_RUN;
    float accn = 0.f, accd = 0.f;
    int cur = -1;
    for (int k = 0; k < POOL_RUN; ++k) {
        int n = n_start + k;
        if (n >= N_NODES) break;
        int g = batch[n];
        if (g != cur) {
            if (cur >= 0) {
                atomicAdd(&num[cur * HD + j], accn);
                atomicAdd(&den[cur * HD + j], accd);
            }
            cur = g;
            accn = 0.f;
            accd = 0.f;
        }
        float v = h[(size_t)n * HD + j];
        float s = expf(ALPHA_ * v);
        accn += v * s;
        accd += s;
    }
    if (cur >= 0) {
        atomicAdd(&num[cur * HD + j], accn);
        atomicAdd(&den[cur * HD + j], accd);
    }
}

__global__ __launch_bounds__(64) void final_kernel(const float* __restrict__ num,
                                                   const float* __restrict__ den,
                                                   const float* __restrict__ w1,
                                                   const float* __restrict__ b1,
                                                   const float* __restrict__ w2,
                                                   const float* __restrict__ b2,
                                                   const float* __restrict__ w3,
                                                   const float* __restrict__ b3,
                                                   float* __restrict__ out) {
    int g = blockIdx.x * blockDim.x + threadIdx.x;
    if (g >= N_GRAPHS) return;
    float p[16];
#pragma unroll
    for (int j = 0; j < 16; ++j) p[j] = num[g * HD + j] / den[g * HD + j];
    float t1[16];
#pragma unroll
    for (int j = 0; j < 16; ++j) {
        float acc = b1[j];
#pragma unroll
        for (int k = 0; k < 16; ++k) acc += p[k] * w1[k * 16 + j];
        t1[j] = fmaxf(acc, 0.f);
    }
    float t2[16];
#pragma unroll
    for (int j = 0; j < 16; ++j) {
        float acc = b2[j];
#pragma unroll
        for (int k = 0; k < 16; ++k) acc += t1[k] * w2[k * 16 + j];
        t2[j] = fmaxf(acc, 0.f);
    }
    float o = b3[0];
#pragma unroll
    for (int k = 0; k < 16; ++k) o += t2[k] * w3[k];
    out[g] = o;
}

extern "C" void kernel_launch(void* const* d_in, const int* in_sizes, int n_in,
                              void* d_out, int out_size, void* d_ws, size_t ws_size,
                              hipStream_t stream) {
    const float* x   = (const float*)d_in[0];
    const int*   ei  = (const int*)d_in[1];
    const int*   src = ei;
    const int*   dst = ei + N_EDGES;
    const int*   batch = (const int*)d_in[2];
    const float* ea  = (const float*)d_in[3];
    const float* cw0 = (const float*)d_in[4];
    const float* cwr = (const float*)d_in[5];
    const float* cb  = (const float*)d_in[6];
    const float* lw  = (const float*)d_in[7];
    const float* lb  = (const float*)d_in[8];
    const float* w1  = (const float*)d_in[9];
    const float* b1  = (const float*)d_in[10];
    const float* w2  = (const float*)d_in[11];
    const float* b2  = (const float*)d_in[12];
    const float* w3  = (const float*)d_in[13];
    const float* b3  = (const float*)d_in[14];
    float* out = (float*)d_out;

    // workspace layout (4-byte units)
    float* ws      = (float*)d_ws;
    float* dinv    = ws;                                   // 200000
    float* s1v     = ws + 200000;                          // 200000
    int*   blkhist = (int*)(ws + 400000);                  // 2443750 (dead after scatter)
    float2* db0    = (float2*)(ws + 400000);               // aliases blkhist; 400000 floats
    int*   bstart  = blkhist + 2443750;                    // 783 (pad 784)
    int*   nodeoff = bstart + 784;                         // 200000 (pad 200010)
    float* num     = (float*)(nodeoff + 200010);           // 16384
    float* den     = num + 16384;                          // 16384
    float2* dx     = (float2*)(den + 16384);               // 400000 floats (offset 3077312, even)
    u64* bucketed  = (u64*)((float*)dx + 400000);          // E u64 (offset 3477312, even)
    u64* sorted    = bucketed + N_EDGES;                   // E u64
    float* h2hat   = (float*)bucketed;                     // alias: free after sortd
    float* h3      = h2hat + (size_t)N_NODES * HD;         // alias (bucketed region)

    hipMemsetAsync(num, 0, (size_t)2 * N_GRAPHS * HD * sizeof(float), stream);

    // full sort by dst: radix pass 1 (bucket dst>>8), pass 2 (in-bucket dlow + dinv/dx)
    hist_kernel<<<NBLKA, 256, 0, stream>>>(dst, blkhist);
    scanA_kernel<<<NBUCK, 256, 0, stream>>>(blkhist, bstart);
    scanB_kernel<<<1, 256, 0, stream>>>(bstart);
    scatter_kernel<<<NBLKA, 256, 0, stream>>>(src, dst, ea, blkhist, bstart, bucketed);
    sortd_kernel<<<NBUCK, 256, 0, stream>>>(bucketed, bstart, x, sorted, nodeoff, dinv, dx);

    // layer 0 (read-only, scalar) -> db0={dinv,base0}, s1
    agg0_kernel<<<NBUCK, 256, 0, stream>>>(sorted, nodeoff, dx, db0, s1v);
    // layer 1 (float2-gather recompute) -> h2hat ; layer 2 (64B-line gather) -> h3
    agg1_kernel<<<12500, 256, 0, stream>>>(sorted, nodeoff, db0, s1v,
                                           cw0, cb, lw, lb,
                                           cwr, cb + 16, lw + 256, lb + 16, h2hat);
    agg2_kernel<<<12500, 256, 0, stream>>>(sorted, nodeoff, h2hat, dinv,
                                           cwr + 256, cb + 32, lw + 512, lb + 32, h3);

    pool_kernel<<<(N_NODES + 16 * POOL_RUN - 1) / (16 * POOL_RUN), 256, 0, stream>>>(h3, batch, num, den);
    final_kernel<<<(N_GRAPHS + 63) / 64, 64, 0, stream>>>(num, den, w1, b1, w2, b2, w3, b3, out);
}

// Round 8
// 415.380 us; speedup vs baseline: 2.4371x; 1.1155x over previous
//
#include <hip/hip_runtime.h>

#define N_NODES 200000
#define N_EDGES 3200000
#define N_GRAPHS 1024
#define HD 16
#define ALPHA_ 0.2f

#define BNODES 256                 // nodes per bucket (dst >> 8)
#define NBUCK 782                  // ceil(N_NODES/256)
#define CHUNKA 1024                // edges per pass-A block
#define NBLKA 3125                 // ceil(N_EDGES/CHUNKA)
#define PERA 13                    // ceil(NBLKA/256)

typedef unsigned long long u64;

// ---------- radix pass 1: bucket by dst>>8 (int LDS atomics only) ----------
__global__ __launch_bounds__(256) void hist_kernel(const int* __restrict__ dst,
                                                   int* __restrict__ blkhist) {
    __shared__ int hist[NBUCK];
    int t = threadIdx.x;
    for (int i = t; i < NBUCK; i += 256) hist[i] = 0;
    __syncthreads();
    int e0 = blockIdx.x * CHUNKA;
    int e1 = min(e0 + CHUNKA, N_EDGES);
    for (int e = e0 + t; e < e1; e += 256)
        atomicAdd(&hist[dst[e] >> 8], 1);
    __syncthreads();
    int* out = blkhist + (size_t)blockIdx.x * NBUCK;
    for (int i = t; i < NBUCK; i += 256) out[i] = hist[i];
}

// column-wise exclusive scan across NBLKA blocks; totals -> bstart
__global__ __launch_bounds__(256) void scanA_kernel(int* __restrict__ blkhist,
                                                    int* __restrict__ bstart) {
    __shared__ int s[256];
    int u = blockIdx.x, t = threadIdx.x;
    int v[PERA];
    int sum = 0;
#pragma unroll
    for (int i = 0; i < PERA; ++i) {
        int j = t * PERA + i;
        v[i] = (j < NBLKA) ? blkhist[(size_t)j * NBUCK + u] : 0;
        sum += v[i];
    }
    s[t] = sum;
    __syncthreads();
    for (int off = 1; off < 256; off <<= 1) {
        int x = (t >= off) ? s[t - off] : 0;
        __syncthreads();
        s[t] += x;
        __syncthreads();
    }
    int run = s[t] - sum;
#pragma unroll
    for (int i = 0; i < PERA; ++i) {
        int j = t * PERA + i;
        if (j < NBLKA) blkhist[(size_t)j * NBUCK + u] = run;
        run += v[i];
    }
    if (t == 255) bstart[u] = s[255];
}

// exclusive scan over bucket totals (single block)
__global__ __launch_bounds__(256) void scanB_kernel(int* __restrict__ bstart) {
    __shared__ int s[256];
    int t = threadIdx.x;
    int v[4];
    int sum = 0;
#pragma unroll
    for (int i = 0; i < 4; ++i) {
        int j = t * 4 + i;
        v[i] = (j < NBUCK) ? bstart[j] : 0;
        sum += v[i];
    }
    s[t] = sum;
    __syncthreads();
    for (int off = 1; off < 256; off <<= 1) {
        int x = (t >= off) ? s[t - off] : 0;
        __syncthreads();
        s[t] += x;
        __syncthreads();
    }
    int run = s[t] - sum;
#pragma unroll
    for (int i = 0; i < 4; ++i) {
        int j = t * 4 + i;
        if (j < NBUCK) bstart[j] = run;
        run += v[i];
    }
    if (t == 255) bstart[NBUCK] = s[255];
}

// entry = (ea:32 | dlow:8 | src:18) — ea stays raw forever (dinv[d] factored out)
__global__ __launch_bounds__(256) void scatter_kernel(const int* __restrict__ src,
                                                      const int* __restrict__ dst,
                                                      const float* __restrict__ ea,
                                                      const int* __restrict__ blkhist,
                                                      const int* __restrict__ bstart,
                                                      u64* __restrict__ bucketed) {
    __shared__ int cursor[NBUCK];
    int t = threadIdx.x;
    const int* bo = blkhist + (size_t)blockIdx.x * NBUCK;
    for (int i = t; i < NBUCK; i += 256) cursor[i] = bstart[i] + bo[i];
    __syncthreads();
    int e0 = blockIdx.x * CHUNKA;
    int e1 = min(e0 + CHUNKA, N_EDGES);
    for (int e = e0 + t; e < e1; e += 256) {
        int d = dst[e];
        int u = d >> 8;
        int pos = atomicAdd(&cursor[u], 1);   // int LDS atomic (native, fast)
        u64 ent = ((u64)__float_as_uint(ea[e]) << 32)
                | (unsigned)(src[e] | ((d & 255) << 18));
        bucketed[pos] = ent;
    }
}

// radix pass 2: in-bucket counting sort by dlow (int LDS atomics) + fused
// per-node weighted degree -> dinv, dx = {dinv, dinv*x}
__global__ __launch_bounds__(256) void sortd_kernel(const u64* __restrict__ bucketed,
                                                    const int* __restrict__ bstart,
                                                    const float* __restrict__ x,
                                                    u64* __restrict__ sorted,
                                                    int* __restrict__ nodeoff,
                                                    float* __restrict__ dinv,
                                                    float2* __restrict__ dx) {
    __shared__ int hist[256];
    __shared__ int s[256];
    __shared__ int cur[256];
    int u = blockIdx.x, t = threadIdx.x;
    hist[t] = 0;
    __syncthreads();
    int b0 = bstart[u], b1 = bstart[u + 1];
    for (int i = b0 + t; i < b1; i += 256)
        atomicAdd(&hist[(int)((bucketed[i] >> 18) & 255u)], 1);
    __syncthreads();
    int c = hist[t];
    s[t] = c;
    __syncthreads();
    for (int off = 1; off < 256; off <<= 1) {
        int v = (t >= off) ? s[t - off] : 0;
        __syncthreads();
        s[t] += v;
        __syncthreads();
    }
    int loc = s[t] - c;   // exclusive
    cur[t] = b0 + loc;
    int n = u * BNODES + t;
    if (n < N_NODES) nodeoff[n] = b0 + loc;
    __syncthreads();
    for (int i = b0 + t; i < b1; i += 256) {
        u64 ent = bucketed[i];
        int pos = atomicAdd(&cur[(int)((ent >> 18) & 255u)], 1);
        sorted[pos] = ent;
    }
    __syncthreads();
    // per-node serial weighted degree over own contiguous range (L1/L2-hot)
    if (n < N_NODES) {
        float sum = 0.f;
        int e0 = b0 + loc;
        for (int k = 0; k < c; ++k)
            sum += __uint_as_float((unsigned)(sorted[e0 + k] >> 32));
        float dn = rsqrtf(sum + 1.0f);
        dinv[n] = dn;
        dx[n] = make_float2(dn, dn * x[n]);
    }
}

// precompute M = lw0 @ cwr0 (16x16) and m2 = lb0 @ cwr0 (16)
__global__ __launch_bounds__(256) void prep_kernel(const float* __restrict__ lw0,
                                                   const float* __restrict__ lb0,
                                                   const float* __restrict__ cwr0,
                                                   float* __restrict__ Mm) {
    int t = threadIdx.x;
    int k = t >> 4, j = t & 15;
    float acc = 0.f;
#pragma unroll
    for (int x = 0; x < 16; ++x) acc += lw0[k * 16 + x] * cwr0[x * 16 + j];
    Mm[t] = acc;
    if (t < 16) {
        float a2 = 0.f;
#pragma unroll
        for (int x = 0; x < 16; ++x) a2 += lb0[x] * cwr0[x * 16 + j];
        Mm[256 + t] = a2;
    }
}

// layer 0 (read-only, unroll-4): base0 = dn*sum(ea*(dinv*x)[s]) + dn^2*x[n]
// s1 = dn*sum(ea*dinv[s]) + dn^2 ; db0[n] = {dinv, base0}
__global__ __launch_bounds__(256) void agg0_kernel(const u64* __restrict__ sorted,
                                                   const int* __restrict__ nodeoff,
                                                   const float2* __restrict__ dx,
                                                   float2* __restrict__ db0,
                                                   float* __restrict__ s1v) {
    int n = blockIdx.x * 256 + threadIdx.x;
    if (n >= N_NODES) return;
    int e0 = nodeoff[n];
    int e1 = (n < N_NODES - 1) ? nodeoff[n + 1] : N_EDGES;
    float2 d2 = dx[n];
    float dn = d2.x;
    float acc = 0.f, wsum = 0.f;
    int i = e0;
    for (; i + 4 <= e1; i += 4) {
        u64 en0 = sorted[i], en1 = sorted[i + 1], en2 = sorted[i + 2], en3 = sorted[i + 3];
        float2 g0 = dx[(int)(en0 & 0x3ffffu)];
        float2 g1 = dx[(int)(en1 & 0x3ffffu)];
        float2 g2 = dx[(int)(en2 & 0x3ffffu)];
        float2 g3 = dx[(int)(en3 & 0x3ffffu)];
        float a0 = __uint_as_float((unsigned)(en0 >> 32));
        float a1 = __uint_as_float((unsigned)(en1 >> 32));
        float a2 = __uint_as_float((unsigned)(en2 >> 32));
        float a3 = __uint_as_float((unsigned)(en3 >> 32));
        acc += a0 * g0.y + a1 * g1.y + a2 * g2.y + a3 * g3.y;
        wsum += a0 * g0.x + a1 * g1.x + a2 * g2.x + a3 * g3.x;
    }
    for (; i < e1; ++i) {
        u64 en = sorted[i];
        float2 g = dx[(int)(en & 0x3ffffu)];
        float a = __uint_as_float((unsigned)(en >> 32));
        acc += a * g.y;
        wsum += a * g.x;
    }
    float base0 = dn * acc + dn * d2.y;     // + dn^2 * x[n]
    db0[n] = make_float2(dn, base0);
    s1v[n] = dn * wsum + dn * dn;
}

// layer 1: thread-per-node edge phase (q[16] in registers, 2 loads/edge total),
// then 16-lane epilogue: v2 = q@M + c*m2 + cb1 ; h2hat = dinv*(relu(v2)@lw1 + lb1)
__global__ __launch_bounds__(256) void agg1_kernel(const u64* __restrict__ sorted,
                                                   const int* __restrict__ nodeoff,
                                                   const float2* __restrict__ db0,
                                                   const float* __restrict__ s1v,
                                                   const float* __restrict__ cw0,
                                                   const float* __restrict__ cb0,
                                                   const float* __restrict__ Mm,
                                                   const float* __restrict__ cb1,
                                                   const float* __restrict__ lw1,
                                                   const float* __restrict__ lb1,
                                                   float* __restrict__ h2hat) {
    __shared__ float sq[256 * 20];   // per node: q[16], c, dn, pad2  (20 KB)
    __shared__ float sa2[256];       // wave-local relu scratch
    int t = threadIdx.x;
    int j = t & 15;
    // per-lane weight columns for the two epilogue matmuls
    float Mc[16], W1c[16];
#pragma unroll
    for (int k = 0; k < 16; ++k) { Mc[k] = Mm[k * 16 + j]; W1c[k] = lw1[k * 16 + j]; }
    float m2j = Mm[256 + j], cb1j = cb1[j], lb1j = lb1[j];
    // per-thread copies of layer-0 conv weights (edge phase computes all 16 j)
    float cwr[16], cbr[16];
#pragma unroll
    for (int k = 0; k < 16; ++k) { cwr[k] = cw0[k]; cbr[k] = cb0[k]; }

    int n = blockIdx.x * 256 + t;
    float q[16];
#pragma unroll
    for (int k = 0; k < 16; ++k) q[k] = 0.f;
    float dn = 0.f, cval = 0.f;
    if (n < N_NODES) {
        int e0 = nodeoff[n];
        int e1 = (n < N_NODES - 1) ? nodeoff[n + 1] : N_EDGES;
        int i = e0;
        for (; i + 4 <= e1; i += 4) {
            u64 en0 = sorted[i], en1 = sorted[i + 1], en2 = sorted[i + 2], en3 = sorted[i + 3];
            float2 g0 = db0[(int)(en0 & 0x3ffffu)];
            float2 g1 = db0[(int)(en1 & 0x3ffffu)];
            float2 g2 = db0[(int)(en2 & 0x3ffffu)];
            float2 g3 = db0[(int)(en3 & 0x3ffffu)];
            float a0 = __uint_as_float((unsigned)(en0 >> 32)) * g0.x;  // ea*dinv[s]
            float a1 = __uint_as_float((unsigned)(en1 >> 32)) * g1.x;
            float a2 = __uint_as_float((unsigned)(en2 >> 32)) * g2.x;
            float a3 = __uint_as_float((unsigned)(en3 >> 32)) * g3.x;
#pragma unroll
            for (int k = 0; k < 16; ++k) {
                q[k] += a0 * fmaxf(g0.y * cwr[k] + cbr[k], 0.f)
                      + a1 * fmaxf(g1.y * cwr[k] + cbr[k], 0.f)
                      + a2 * fmaxf(g2.y * cwr[k] + cbr[k], 0.f)
                      + a3 * fmaxf(g3.y * cwr[k] + cbr[k], 0.f);
            }
        }
        for (; i < e1; ++i) {
            u64 en = sorted[i];
            float2 g = db0[(int)(en & 0x3ffffu)];
            float a = __uint_as_float((unsigned)(en >> 32)) * g.x;
#pragma unroll
            for (int k = 0; k < 16; ++k)
                q[k] += a * fmaxf(g.y * cwr[k] + cbr[k], 0.f);
        }
        float2 self = db0[n];
        dn = self.x;
        float ds = dn * dn;
#pragma unroll
        for (int k = 0; k < 16; ++k)
            q[k] = dn * q[k] + ds * fmaxf(self.y * cwr[k] + cbr[k], 0.f);
        cval = s1v[n];
    }
    // dump q, c, dn to LDS
    float* row = sq + t * 20;
#pragma unroll
    for (int k = 0; k < 16; k += 4)
        *(float4*)(row + k) = make_float4(q[k], q[k + 1], q[k + 2], q[k + 3]);
    row[16] = cval;
    row[17] = dn;
    __syncthreads();
    // epilogue: 16 groups x 16 lanes; each group iterates its 16 nodes
    int g = t >> 4;
    float* ar = sa2 + g * 16;
    for (int it = 0; it < 16; ++it) {
        int nl = g * 16 + it;
        const float* r = sq + nl * 20;
        float4 q0 = *(const float4*)(r);
        float4 q1 = *(const float4*)(r + 4);
        float4 q2 = *(const float4*)(r + 8);
        float4 q3 = *(const float4*)(r + 12);
        float c2 = r[16], dn2 = r[17];
        float v2 = c2 * m2j + cb1j;
        v2 += q0.x * Mc[0] + q0.y * Mc[1] + q0.z * Mc[2] + q0.w * Mc[3];
        v2 += q1.x * Mc[4] + q1.y * Mc[5] + q1.z * Mc[6] + q1.w * Mc[7];
        v2 += q2.x * Mc[8] + q2.y * Mc[9] + q2.z * Mc[10] + q2.w * Mc[11];
        v2 += q3.x * Mc[12] + q3.y * Mc[13] + q3.z * Mc[14] + q3.w * Mc[15];
        ar[j] = fmaxf(v2, 0.f);          // wave-local (group within one wave)
        float o = lb1j;
#pragma unroll
        for (int k = 0; k < 16; ++k) o += ar[k] * W1c[k];
        int n2 = blockIdx.x * 256 + nl;
        if (n2 < N_NODES) h2hat[(size_t)n2 * 16 + j] = dn2 * o;
    }
}

// layer 2: 16 lanes/node, unroll-8 coalesced 64B line gathers of h2hat[s][:];
// epilogue via register weight-columns + wave-local LDS roundtrip (no shuffles)
__global__ __launch_bounds__(256) void agg2_kernel(const u64* __restrict__ sorted,
                                                   const int* __restrict__ nodeoff,
                                                   const float* __restrict__ h2hat,
                                                   const float* __restrict__ dinv,
                                                   const float* __restrict__ cwr1,
                                                   const float* __restrict__ cb2,
                                                   const float* __restrict__ lw2,
                                                   const float* __restrict__ lb2,
                                                   float* __restrict__ h3) {
    __shared__ float sz[256];   // per (group, j) — wave-local roundtrip
    int t = threadIdx.x, j = t & 15, g = t >> 4;
    float W1c[16], W2c[16];
#pragma unroll
    for (int k = 0; k < 16; ++k) { W1c[k] = cwr1[k * 16 + j]; W2c[k] = lw2[k * 16 + j]; }
    float cb2j = cb2[j], lb2j = lb2[j];
    int n = blockIdx.x * 16 + g;             // 12500 * 16 = 200000 exactly
    int e0 = nodeoff[n];
    int e1 = (n < N_NODES - 1) ? nodeoff[n + 1] : N_EDGES;
    float q = 0.f;
    int i = e0;
    for (; i + 8 <= e1; i += 8) {
        u64 en0 = sorted[i],     en1 = sorted[i + 1], en2 = sorted[i + 2], en3 = sorted[i + 3];
        u64 en4 = sorted[i + 4], en5 = sorted[i + 5], en6 = sorted[i + 6], en7 = sorted[i + 7];
        float g0 = h2hat[(size_t)(en0 & 0x3ffffu) * 16 + j];
        float g1 = h2hat[(size_t)(en1 & 0x3ffffu) * 16 + j];
        float g2 = h2hat[(size_t)(en2 & 0x3ffffu) * 16 + j];
        float g3 = h2hat[(size_t)(en3 & 0x3ffffu) * 16 + j];
        float g4 = h2hat[(size_t)(en4 & 0x3ffffu) * 16 + j];
        float g5 = h2hat[(size_t)(en5 & 0x3ffffu) * 16 + j];
        float g6 = h2hat[(size_t)(en6 & 0x3ffffu) * 16 + j];
        float g7 = h2hat[(size_t)(en7 & 0x3ffffu) * 16 + j];
        q += __uint_as_float((unsigned)(en0 >> 32)) * g0
           + __uint_as_float((unsigned)(en1 >> 32)) * g1
           + __uint_as_float((unsigned)(en2 >> 32)) * g2
           + __uint_as_float((unsigned)(en3 >> 32)) * g3
           + __uint_as_float((unsigned)(en4 >> 32)) * g4
           + __uint_as_float((unsigned)(en5 >> 32)) * g5
           + __uint_as_float((unsigned)(en6 >> 32)) * g6
           + __uint_as_float((unsigned)(en7 >> 32)) * g7;
    }
    for (; i < e1; ++i) {
        u64 en = sorted[i];
        q += __uint_as_float((unsigned)(en >> 32)) * h2hat[(size_t)(en & 0x3ffffu) * 16 + j];
    }
    float dn = dinv[n];
    float z = dn * (q + h2hat[(size_t)n * 16 + j]);   // + dn^2 * h2[n]
    const float* zr = sz + g * 16;
    sz[t] = z;                                        // wave-local
    float v = cb2j;
#pragma unroll
    for (int k = 0; k < 16; ++k) v += zr[k] * W1c[k];
    float a = fmaxf(v, 0.f);
    sz[t] = a;                                        // wave-local overwrite
    float o = lb2j;
#pragma unroll
    for (int k = 0; k < 16; ++k) o += zr[k] * W2c[k];
    h3[(size_t)n * 16 + j] = o;
}

// segmented pooling over sorted batch (~116k global fp atomics total)
#define POOL_RUN 32
__global__ __launch_bounds__(256) void pool_kernel(const float* __restrict__ h,
                                                   const int* __restrict__ batch,
                                                   float* __restrict__ num,
                                                   float* __restrict__ den) {
    int t = threadIdx.x;
    int tg = t >> 4, j = t & 15;
    int n_start = blockIdx.x * (16 * POOL_RUN) + tg * POOL_RUN;
    float accn = 0.f, accd = 0.f;
    int cur = -1;
    for (int k = 0; k < POOL_RUN; ++k) {
        int n = n_start + k;
        if (n >= N_NODES) break;
        int g = batch[n];
        if (g != cur) {
            if (cur >= 0) {
                atomicAdd(&num[cur * HD + j], accn);
                atomicAdd(&den[cur * HD + j], accd);
            }
            cur = g;
            accn = 0.f;
            accd = 0.f;
        }
        float v = h[(size_t)n * HD + j];
        float s = expf(ALPHA_ * v);
        accn += v * s;
        accd += s;
    }
    if (cur >= 0) {
        atomicAdd(&num[cur * HD + j], accn);
        atomicAdd(&den[cur * HD + j], accd);
    }
}

__global__ __launch_bounds__(64) void final_kernel(const float* __restrict__ num,
                                                   const float* __restrict__ den,
                                                   const float* __restrict__ w1,
                                                   const float* __restrict__ b1,
                                                   const float* __restrict__ w2,
                                                   const float* __restrict__ b2,
                                                   const float* __restrict__ w3,
                                                   const float* __restrict__ b3,
                                                   float* __restrict__ out) {
    int g = blockIdx.x * blockDim.x + threadIdx.x;
    if (g >= N_GRAPHS) return;
    float p[16];
#pragma unroll
    for (int j = 0; j < 16; ++j) p[j] = num[g * HD + j] / den[g * HD + j];
    float t1[16];
#pragma unroll
    for (int j = 0; j < 16; ++j) {
        float acc = b1[j];
#pragma unroll
        for (int k = 0; k < 16; ++k) acc += p[k] * w1[k * 16 + j];
        t1[j] = fmaxf(acc, 0.f);
    }
    float t2[16];
#pragma unroll
    for (int j = 0; j < 16; ++j) {
        float acc = b2[j];
#pragma unroll
        for (int k = 0; k < 16; ++k) acc += t1[k] * w2[k * 16 + j];
        t2[j] = fmaxf(acc, 0.f);
    }
    float o = b3[0];
#pragma unroll
    for (int k = 0; k < 16; ++k) o += t2[k] * w3[k];
    out[g] = o;
}

extern "C" void kernel_launch(void* const* d_in, const int* in_sizes, int n_in,
                              void* d_out, int out_size, void* d_ws, size_t ws_size,
                              hipStream_t stream) {
    const float* x   = (const float*)d_in[0];
    const int*   ei  = (const int*)d_in[1];
    const int*   src = ei;
    const int*   dst = ei + N_EDGES;
    const int*   batch = (const int*)d_in[2];
    const float* ea  = (const float*)d_in[3];
    const float* cw0 = (const float*)d_in[4];
    const float* cwr = (const float*)d_in[5];
    const float* cb  = (const float*)d_in[6];
    const float* lw  = (const float*)d_in[7];
    const float* lb  = (const float*)d_in[8];
    const float* w1  = (const float*)d_in[9];
    const float* b1  = (const float*)d_in[10];
    const float* w2  = (const float*)d_in[11];
    const float* b2  = (const float*)d_in[12];
    const float* w3  = (const float*)d_in[13];
    const float* b3  = (const float*)d_in[14];
    float* out = (float*)d_out;

    // workspace layout (4-byte units)
    float* ws      = (float*)d_ws;
    float* dinv    = ws;                                   // 200000
    float* s1v     = ws + 200000;                          // 200000
    int*   blkhist = (int*)(ws + 400000);                  // 2443750 (dead after scatter)
    float2* db0    = (float2*)(ws + 400000);               // aliases blkhist; 400000 floats
    int*   bstart  = blkhist + 2443750;                    // 783 (pad 784)
    int*   nodeoff = bstart + 784;                         // 200000 (pad 200010)
    float* num     = (float*)(nodeoff + 200010);           // 16384
    float* den     = num + 16384;                          // 16384
    float* Mm      = den + 16384;                          // 272 (pad 288)
    float2* dx     = (float2*)(Mm + 288);                  // 400000 floats (even offset)
    u64* bucketed  = (u64*)((float*)dx + 400000);          // E u64 (even offset)
    u64* sorted    = bucketed + N_EDGES;                   // E u64
    float* h2hat   = (float*)bucketed;                     // alias: free after sortd
    float* h3      = h2hat + (size_t)N_NODES * HD;         // alias (bucketed region)

    hipMemsetAsync(num, 0, (size_t)2 * N_GRAPHS * HD * sizeof(float), stream);

    // precompute M = lw0@cwr0, m2 = lb0@cwr0 (independent of sort)
    prep_kernel<<<1, 256, 0, stream>>>(lw, lb, cwr, Mm);

    // full sort by dst: radix pass 1 (bucket dst>>8), pass 2 (in-bucket dlow + dinv/dx)
    hist_kernel<<<NBLKA, 256, 0, stream>>>(dst, blkhist);
    scanA_kernel<<<NBUCK, 256, 0, stream>>>(blkhist, bstart);
    scanB_kernel<<<1, 256, 0, stream>>>(bstart);
    scatter_kernel<<<NBLKA, 256, 0, stream>>>(src, dst, ea, blkhist, bstart, bucketed);
    sortd_kernel<<<NBUCK, 256, 0, stream>>>(bucketed, bstart, x, sorted, nodeoff, dinv, dx);

    // layer 0 (read-only, scalar) -> db0={dinv,base0}, s1
    agg0_kernel<<<NBUCK, 256, 0, stream>>>(sorted, nodeoff, dx, db0, s1v);
    // layer 1 (thread-per-node + fused 2-stage epilogue) -> h2hat
    agg1_kernel<<<NBUCK, 256, 0, stream>>>(sorted, nodeoff, db0, s1v,
                                           cw0, cb, Mm, cb + 16, lw + 256, lb + 16, h2hat);
    // layer 2 (64B-line gather, unroll-8) -> h3
    agg2_kernel<<<12500, 256, 0, stream>>>(sorted, nodeoff, h2hat, dinv,
                                           cwr + 256, cb + 32, lw + 512, lb + 32, h3);

    pool_kernel<<<(N_NODES + 16 * POOL_RUN - 1) / (16 * POOL_RUN), 256, 0, stream>>>(h3, batch, num, den);
    final_kernel<<<(N_GRAPHS + 63) / 64, 64, 0, stream>>>(num, den, w1, b1, w2, b2, w3, b3, out);
}

// Round 9
// 381.805 us; speedup vs baseline: 2.6514x; 1.0879x over previous
//
#include <hip/hip_runtime.h>

#define N_NODES 200000
#define N_EDGES 3200000
#define N_GRAPHS 1024
#define HD 16
#define ALPHA_ 0.2f

#define BNODES 256                 // nodes per bucket (dst >> 8)
#define NBUCK 782                  // ceil(N_NODES/256)
#define CHUNKA 4096                // edges per pass-A block
#define NBLKA 782                  // ceil(N_EDGES/CHUNKA) = 781.25 -> 782
#define PERA 4                     // ceil(NBLKA/256)

typedef unsigned long long u64;

// ---------- radix pass 1: bucket by dst>>8 (int LDS atomics only) ----------
__global__ __launch_bounds__(256) void hist_kernel(const int* __restrict__ dst,
                                                   int* __restrict__ blkhist) {
    __shared__ int hist[NBUCK];
    int t = threadIdx.x;
    for (int i = t; i < NBUCK; i += 256) hist[i] = 0;
    __syncthreads();
    int e0 = blockIdx.x * CHUNKA;
    int e1 = min(e0 + CHUNKA, N_EDGES);
#pragma unroll
    for (int k = 0; k < 4; ++k) {
        int e = e0 + (k << 10) + (t << 2);
        if (e < e1) {   // e, e1 both multiples of 4 -> full int4 valid
            int4 d4 = *(const int4*)(dst + e);
            atomicAdd(&hist[d4.x >> 8], 1);
            atomicAdd(&hist[d4.y >> 8], 1);
            atomicAdd(&hist[d4.z >> 8], 1);
            atomicAdd(&hist[d4.w >> 8], 1);
        }
    }
    __syncthreads();
    int* out = blkhist + (size_t)blockIdx.x * NBUCK;
    for (int i = t; i < NBUCK; i += 256) out[i] = hist[i];
}

// column-wise exclusive scan across NBLKA blocks; totals -> bstart
__global__ __launch_bounds__(256) void scanA_kernel(int* __restrict__ blkhist,
                                                    int* __restrict__ bstart) {
    __shared__ int s[256];
    int u = blockIdx.x, t = threadIdx.x;
    int v[PERA];
    int sum = 0;
#pragma unroll
    for (int i = 0; i < PERA; ++i) {
        int j = t * PERA + i;
        v[i] = (j < NBLKA) ? blkhist[(size_t)j * NBUCK + u] : 0;
        sum += v[i];
    }
    s[t] = sum;
    __syncthreads();
    for (int off = 1; off < 256; off <<= 1) {
        int x = (t >= off) ? s[t - off] : 0;
        __syncthreads();
        s[t] += x;
        __syncthreads();
    }
    int run = s[t] - sum;
#pragma unroll
    for (int i = 0; i < PERA; ++i) {
        int j = t * PERA + i;
        if (j < NBLKA) blkhist[(size_t)j * NBUCK + u] = run;
        run += v[i];
    }
    if (t == 255) bstart[u] = s[255];
}

// exclusive scan over bucket totals (single block)
__global__ __launch_bounds__(256) void scanB_kernel(int* __restrict__ bstart) {
    __shared__ int s[256];
    int t = threadIdx.x;
    int v[4];
    int sum = 0;
#pragma unroll
    for (int i = 0; i < 4; ++i) {
        int j = t * 4 + i;
        v[i] = (j < NBUCK) ? bstart[j] : 0;
        sum += v[i];
    }
    s[t] = sum;
    __syncthreads();
    for (int off = 1; off < 256; off <<= 1) {
        int x = (t >= off) ? s[t - off] : 0;
        __syncthreads();
        s[t] += x;
        __syncthreads();
    }
    int run = s[t] - sum;
#pragma unroll
    for (int i = 0; i < 4; ++i) {
        int j = t * 4 + i;
        if (j < NBUCK) bstart[j] = run;
        run += v[i];
    }
    if (t == 255) bstart[NBUCK] = s[255];
}

// entry = (ea:32 | dlow:8 | src:18) — ea stays raw (dinv[d] factored out)
__global__ __launch_bounds__(256) void scatter_kernel(const int* __restrict__ src,
                                                      const int* __restrict__ dst,
                                                      const float* __restrict__ ea,
                                                      const int* __restrict__ blkhist,
                                                      const int* __restrict__ bstart,
                                                      u64* __restrict__ bucketed) {
    __shared__ int cursor[NBUCK];
    int t = threadIdx.x;
    const int* bo = blkhist + (size_t)blockIdx.x * NBUCK;
    for (int i = t; i < NBUCK; i += 256) cursor[i] = bstart[i] + bo[i];
    __syncthreads();
    int e0 = blockIdx.x * CHUNKA;
    int e1 = min(e0 + CHUNKA, N_EDGES);
#pragma unroll
    for (int k = 0; k < 4; ++k) {
        int e = e0 + (k << 10) + (t << 2);
        if (e < e1) {   // full int4/float4 valid (multiples of 4)
            int4   d4 = *(const int4*)(dst + e);
            int4   s4 = *(const int4*)(src + e);
            float4 a4 = *(const float4*)(ea + e);
            int p0 = atomicAdd(&cursor[d4.x >> 8], 1);
            int p1 = atomicAdd(&cursor[d4.y >> 8], 1);
            int p2 = atomicAdd(&cursor[d4.z >> 8], 1);
            int p3 = atomicAdd(&cursor[d4.w >> 8], 1);
            bucketed[p0] = ((u64)__float_as_uint(a4.x) << 32) | (unsigned)(s4.x | ((d4.x & 255) << 18));
            bucketed[p1] = ((u64)__float_as_uint(a4.y) << 32) | (unsigned)(s4.y | ((d4.y & 255) << 18));
            bucketed[p2] = ((u64)__float_as_uint(a4.z) << 32) | (unsigned)(s4.z | ((d4.z & 255) << 18));
            bucketed[p3] = ((u64)__float_as_uint(a4.w) << 32) | (unsigned)(s4.w | ((d4.w & 255) << 18));
        }
    }
}

// radix pass 2: in-bucket counting sort by dlow (int LDS atomics) + fused
// per-node weighted degree -> dinv, dx = {dinv, dinv*x}
__global__ __launch_bounds__(256) void sortd_kernel(const u64* __restrict__ bucketed,
                                                    const int* __restrict__ bstart,
                                                    const float* __restrict__ x,
                                                    u64* __restrict__ sorted,
                                                    int* __restrict__ nodeoff,
                                                    float* __restrict__ dinv,
                                                    float2* __restrict__ dx) {
    __shared__ int hist[256];
    __shared__ int s[256];
    __shared__ int cur[256];
    int u = blockIdx.x, t = threadIdx.x;
    hist[t] = 0;
    __syncthreads();
    int b0 = bstart[u], b1 = bstart[u + 1];
    for (int i = b0 + t; i < b1; i += 256)
        atomicAdd(&hist[(int)((bucketed[i] >> 18) & 255u)], 1);
    __syncthreads();
    int c = hist[t];
    s[t] = c;
    __syncthreads();
    for (int off = 1; off < 256; off <<= 1) {
        int v = (t >= off) ? s[t - off] : 0;
        __syncthreads();
        s[t] += v;
        __syncthreads();
    }
    int loc = s[t] - c;   // exclusive
    cur[t] = b0 + loc;
    int n = u * BNODES + t;
    if (n < N_NODES) nodeoff[n] = b0 + loc;
    __syncthreads();
    for (int i = b0 + t; i < b1; i += 256) {
        u64 ent = bucketed[i];
        int pos = atomicAdd(&cur[(int)((ent >> 18) & 255u)], 1);
        sorted[pos] = ent;
    }
    __syncthreads();
    // per-node serial weighted degree over own contiguous range (L1/L2-hot)
    if (n < N_NODES) {
        float sum = 0.f;
        int e0 = b0 + loc;
        for (int k = 0; k < c; ++k)
            sum += __uint_as_float((unsigned)(sorted[e0 + k] >> 32));
        float dn = rsqrtf(sum + 1.0f);
        dinv[n] = dn;
        dx[n] = make_float2(dn, dn * x[n]);
    }
}

// layer 0 (read-only, unroll-4): base0 = dn*sum(ea*(dinv*x)[s]) + dn^2*x[n]
// s1 = dn*sum(ea*dinv[s]) + dn^2 ; db0[n] = {dinv, base0}
__global__ __launch_bounds__(256) void agg0_kernel(const u64* __restrict__ sorted,
                                                   const int* __restrict__ nodeoff,
                                                   const float2* __restrict__ dx,
                                                   float2* __restrict__ db0,
                                                   float* __restrict__ s1v) {
    int n = blockIdx.x * 256 + threadIdx.x;
    if (n >= N_NODES) return;
    int e0 = nodeoff[n];
    int e1 = (n < N_NODES - 1) ? nodeoff[n + 1] : N_EDGES;
    float2 d2 = dx[n];
    float dn = d2.x;
    float acc = 0.f, wsum = 0.f;
    int i = e0;
    for (; i + 4 <= e1; i += 4) {
        u64 en0 = sorted[i], en1 = sorted[i + 1], en2 = sorted[i + 2], en3 = sorted[i + 3];
        float2 g0 = dx[(int)(en0 & 0x3ffffu)];
        float2 g1 = dx[(int)(en1 & 0x3ffffu)];
        float2 g2 = dx[(int)(en2 & 0x3ffffu)];
        float2 g3 = dx[(int)(en3 & 0x3ffffu)];
        float a0 = __uint_as_float((unsigned)(en0 >> 32));
        float a1 = __uint_as_float((unsigned)(en1 >> 32));
        float a2 = __uint_as_float((unsigned)(en2 >> 32));
        float a3 = __uint_as_float((unsigned)(en3 >> 32));
        acc += a0 * g0.y + a1 * g1.y + a2 * g2.y + a3 * g3.y;
        wsum += a0 * g0.x + a1 * g1.x + a2 * g2.x + a3 * g3.x;
    }
    for (; i < e1; ++i) {
        u64 en = sorted[i];
        float2 g = dx[(int)(en & 0x3ffffu)];
        float a = __uint_as_float((unsigned)(en >> 32));
        acc += a * g.y;
        wsum += a * g.x;
    }
    float base0 = dn * acc + dn * d2.y;     // + dn^2 * x[n]
    db0[n] = make_float2(dn, base0);
    s1v[n] = dn * wsum + dn * dn;
}

// layer 1: thread-per-node edge phase (q[16] in registers, 2 loads/edge total),
// then 16-lane epilogue: v2 = q@M + c*m2 + cb1 ; h2hat = dinv*(relu(v2)@lw1 + lb1)
// M = lw0@cwr0 and m2 = lb0@cwr0 computed block-locally in LDS (prep fused in)
__global__ __launch_bounds__(256) void agg1_kernel(const u64* __restrict__ sorted,
                                                   const int* __restrict__ nodeoff,
                                                   const float2* __restrict__ db0,
                                                   const float* __restrict__ s1v,
                                                   const float* __restrict__ cw0,
                                                   const float* __restrict__ cb0,
                                                   const float* __restrict__ lw0,
                                                   const float* __restrict__ lb0,
                                                   const float* __restrict__ cwr0,
                                                   const float* __restrict__ cb1,
                                                   const float* __restrict__ lw1,
                                                   const float* __restrict__ lb1,
                                                   float* __restrict__ h2hat) {
    __shared__ float sq[256 * 20];   // per node: q[16], c, dn, pad2  (20 KB)
    __shared__ float sa2[256];       // wave-local relu scratch
    __shared__ float sM[256];        // M = lw0 @ cwr0
    __shared__ float sm2[16];        // m2 = lb0 @ cwr0
    int t = threadIdx.x;
    int j = t & 15;
    {   // fused prep: M[t] with row=t>>4, col=t&15
        int kk = t >> 4;
        float accM = 0.f;
#pragma unroll
        for (int xx = 0; xx < 16; ++xx) accM += lw0[kk * 16 + xx] * cwr0[xx * 16 + j];
        sM[t] = accM;
        if (t < 16) {
            float a2 = 0.f;
#pragma unroll
            for (int xx = 0; xx < 16; ++xx) a2 += lb0[xx] * cwr0[xx * 16 + t];
            sm2[t] = a2;
        }
    }
    __syncthreads();
    // per-lane weight columns for the two epilogue matmuls
    float Mc[16], W1c[16];
#pragma unroll
    for (int k = 0; k < 16; ++k) { Mc[k] = sM[k * 16 + j]; W1c[k] = lw1[k * 16 + j]; }
    float m2j = sm2[j], cb1j = cb1[j], lb1j = lb1[j];
    // per-thread copies of layer-0 conv weights (edge phase computes all 16 j)
    float cwr[16], cbr[16];
#pragma unroll
    for (int k = 0; k < 16; ++k) { cwr[k] = cw0[k]; cbr[k] = cb0[k]; }

    int n = blockIdx.x * 256 + t;
    float q[16];
#pragma unroll
    for (int k = 0; k < 16; ++k) q[k] = 0.f;
    float dn = 0.f, cval = 0.f;
    if (n < N_NODES) {
        int e0 = nodeoff[n];
        int e1 = (n < N_NODES - 1) ? nodeoff[n + 1] : N_EDGES;
        int i = e0;
        for (; i + 4 <= e1; i += 4) {
            u64 en0 = sorted[i], en1 = sorted[i + 1], en2 = sorted[i + 2], en3 = sorted[i + 3];
            float2 g0 = db0[(int)(en0 & 0x3ffffu)];
            float2 g1 = db0[(int)(en1 & 0x3ffffu)];
            float2 g2 = db0[(int)(en2 & 0x3ffffu)];
            float2 g3 = db0[(int)(en3 & 0x3ffffu)];
            float a0 = __uint_as_float((unsigned)(en0 >> 32)) * g0.x;  // ea*dinv[s]
            float a1 = __uint_as_float((unsigned)(en1 >> 32)) * g1.x;
            float a2 = __uint_as_float((unsigned)(en2 >> 32)) * g2.x;
            float a3 = __uint_as_float((unsigned)(en3 >> 32)) * g3.x;
#pragma unroll
            for (int k = 0; k < 16; ++k) {
                q[k] += a0 * fmaxf(g0.y * cwr[k] + cbr[k], 0.f)
                      + a1 * fmaxf(g1.y * cwr[k] + cbr[k], 0.f)
                      + a2 * fmaxf(g2.y * cwr[k] + cbr[k], 0.f)
                      + a3 * fmaxf(g3.y * cwr[k] + cbr[k], 0.f);
            }
        }
        for (; i < e1; ++i) {
            u64 en = sorted[i];
            float2 g = db0[(int)(en & 0x3ffffu)];
            float a = __uint_as_float((unsigned)(en >> 32)) * g.x;
#pragma unroll
            for (int k = 0; k < 16; ++k)
                q[k] += a * fmaxf(g.y * cwr[k] + cbr[k], 0.f);
        }
        float2 self = db0[n];
        dn = self.x;
        float ds = dn * dn;
#pragma unroll
        for (int k = 0; k < 16; ++k)
            q[k] = dn * q[k] + ds * fmaxf(self.y * cwr[k] + cbr[k], 0.f);
        cval = s1v[n];
    }
    // dump q, c, dn to LDS
    float* row = sq + t * 20;
#pragma unroll
    for (int k = 0; k < 16; k += 4)
        *(float4*)(row + k) = make_float4(q[k], q[k + 1], q[k + 2], q[k + 3]);
    row[16] = cval;
    row[17] = dn;
    __syncthreads();
    // epilogue: 16 groups x 16 lanes; each group iterates its 16 nodes
    int g = t >> 4;
    float* ar = sa2 + g * 16;
    for (int it = 0; it < 16; ++it) {
        int nl = g * 16 + it;
        const float* r = sq + nl * 20;
        float4 q0 = *(const float4*)(r);
        float4 q1 = *(const float4*)(r + 4);
        float4 q2 = *(const float4*)(r + 8);
        float4 q3 = *(const float4*)(r + 12);
        float c2 = r[16], dn2 = r[17];
        float v2 = c2 * m2j + cb1j;
        v2 += q0.x * Mc[0] + q0.y * Mc[1] + q0.z * Mc[2] + q0.w * Mc[3];
        v2 += q1.x * Mc[4] + q1.y * Mc[5] + q1.z * Mc[6] + q1.w * Mc[7];
        v2 += q2.x * Mc[8] + q2.y * Mc[9] + q2.z * Mc[10] + q2.w * Mc[11];
        v2 += q3.x * Mc[12] + q3.y * Mc[13] + q3.z * Mc[14] + q3.w * Mc[15];
        ar[j] = fmaxf(v2, 0.f);          // wave-local (group within one wave)
        float o = lb1j;
#pragma unroll
        for (int k = 0; k < 16; ++k) o += ar[k] * W1c[k];
        int n2 = blockIdx.x * 256 + nl;
        if (n2 < N_NODES) h2hat[(size_t)n2 * 16 + j] = dn2 * o;
    }
}

// layer 2: 16 lanes per group, 4 nodes serially per group (weight setup amortized);
// unroll-8 coalesced 64B line gathers of h2hat[s][:]; wave-local LDS epilogue
__global__ __launch_bounds__(256) void agg2_kernel(const u64* __restrict__ sorted,
                                                   const int* __restrict__ nodeoff,
                                                   const float* __restrict__ h2hat,
                                                   const float* __restrict__ dinv,
                                                   const float* __restrict__ cwr1,
                                                   const float* __restrict__ cb2,
                                                   const float* __restrict__ lw2,
                                                   const float* __restrict__ lb2,
                                                   float* __restrict__ h3) {
    __shared__ float sz[256];   // per (group, j) — wave-local roundtrip
    int t = threadIdx.x, j = t & 15, g = t >> 4;
    float W1c[16], W2c[16];
#pragma unroll
    for (int k = 0; k < 16; ++k) { W1c[k] = cwr1[k * 16 + j]; W2c[k] = lw2[k * 16 + j]; }
    float cb2j = cb2[j], lb2j = lb2[j];
    const float* zr = sz + g * 16;
    int nbase = blockIdx.x * 64 + g * 4;     // 3125 * 64 = 200000 exactly
#pragma unroll
    for (int it = 0; it < 4; ++it) {
        int n = nbase + it;
        int e0 = nodeoff[n];
        int e1 = (n < N_NODES - 1) ? nodeoff[n + 1] : N_EDGES;
        float q = 0.f;
        int i = e0;
        for (; i + 8 <= e1; i += 8) {
            u64 en0 = sorted[i],     en1 = sorted[i + 1], en2 = sorted[i + 2], en3 = sorted[i + 3];
            u64 en4 = sorted[i + 4], en5 = sorted[i + 5], en6 = sorted[i + 6], en7 = sorted[i + 7];
            float g0 = h2hat[(size_t)(en0 & 0x3ffffu) * 16 + j];
            float g1 = h2hat[(size_t)(en1 & 0x3ffffu) * 16 + j];
            float g2 = h2hat[(size_t)(en2 & 0x3ffffu) * 16 + j];
            float g3 = h2hat[(size_t)(en3 & 0x3ffffu) * 16 + j];
            float g4 = h2hat[(size_t)(en4 & 0x3ffffu) * 16 + j];
            float g5 = h2hat[(size_t)(en5 & 0x3ffffu) * 16 + j];
            float g6 = h2hat[(size_t)(en6 & 0x3ffffu) * 16 + j];
            float g7 = h2hat[(size_t)(en7 & 0x3ffffu) * 16 + j];
            q += __uint_as_float((unsigned)(en0 >> 32)) * g0
               + __uint_as_float((unsigned)(en1 >> 32)) * g1
               + __uint_as_float((unsigned)(en2 >> 32)) * g2
               + __uint_as_float((unsigned)(en3 >> 32)) * g3
               + __uint_as_float((unsigned)(en4 >> 32)) * g4
               + __uint_as_float((unsigned)(en5 >> 32)) * g5
               + __uint_as_float((unsigned)(en6 >> 32)) * g6
               + __uint_as_float((unsigned)(en7 >> 32)) * g7;
        }
        for (; i < e1; ++i) {
            u64 en = sorted[i];
            q += __uint_as_float((unsigned)(en >> 32)) * h2hat[(size_t)(en & 0x3ffffu) * 16 + j];
        }
        float dn = dinv[n];
        float z = dn * (q + h2hat[(size_t)n * 16 + j]);   // + dn^2 * h2[n]
        sz[t] = z;                                        // wave-local
        float v = cb2j;
#pragma unroll
        for (int k = 0; k < 16; ++k) v += zr[k] * W1c[k];
        float a = fmaxf(v, 0.f);
        sz[t] = a;                                        // wave-local overwrite
        float o = lb2j;
#pragma unroll
        for (int k = 0; k < 16; ++k) o += zr[k] * W2c[k];
        h3[(size_t)n * 16 + j] = o;
    }
}

// segmented pooling over sorted batch (~116k global fp atomics total)
#define POOL_RUN 32
__global__ __launch_bounds__(256) void pool_kernel(const float* __restrict__ h,
                                                   const int* __restrict__ batch,
                                                   float* __restrict__ num,
                                                   float* __restrict__ den) {
    int t = threadIdx.x;
    int tg = t >> 4, j = t & 15;
    int n_start = blockIdx.x * (16 * POOL_RUN) + tg * POOL_RUN;
    float accn = 0.f, accd = 0.f;
    int cur = -1;
    for (int k = 0; k < POOL_RUN; ++k) {
        int n = n_start + k;
        if (n >= N_NODES) break;
        int g = batch[n];
        if (g != cur) {
            if (cur >= 0) {
                atomicAdd(&num[cur * HD + j], accn);
                atomicAdd(&den[cur * HD + j], accd);
            }
            cur = g;
            accn = 0.f;
            accd = 0.f;
        }
        float v = h[(size_t)n * HD + j];
        float s = expf(ALPHA_ * v);
        accn += v * s;
        accd += s;
    }
    if (cur >= 0) {
        atomicAdd(&num[cur * HD + j], accn);
        atomicAdd(&den[cur * HD + j], accd);
    }
}

__global__ __launch_bounds__(64) void final_kernel(const float* __restrict__ num,
                                                   const float* __restrict__ den,
                                                   const float* __restrict__ w1,
                                                   const float* __restrict__ b1,
                                                   const float* __restrict__ w2,
                                                   const float* __restrict__ b2,
                                                   const float* __restrict__ w3,
                                                   const float* __restrict__ b3,
                                                   float* __restrict__ out) {
    int g = blockIdx.x * blockDim.x + threadIdx.x;
    if (g >= N_GRAPHS) return;
    float p[16];
#pragma unroll
    for (int j = 0; j < 16; ++j) p[j] = num[g * HD + j] / den[g * HD + j];
    float t1[16];
#pragma unroll
    for (int j = 0; j < 16; ++j) {
        float acc = b1[j];
#pragma unroll
        for (int k = 0; k < 16; ++k) acc += p[k] * w1[k * 16 + j];
        t1[j] = fmaxf(acc, 0.f);
    }
    float t2[16];
#pragma unroll
    for (int j = 0; j < 16; ++j) {
        float acc = b2[j];
#pragma unroll
        for (int k = 0; k < 16; ++k) acc += t1[k] * w2[k * 16 + j];
        t2[j] = fmaxf(acc, 0.f);
    }
    float o = b3[0];
#pragma unroll
    for (int k = 0; k < 16; ++k) o += t2[k] * w3[k];
    out[g] = o;
}

extern "C" void kernel_launch(void* const* d_in, const int* in_sizes, int n_in,
                              void* d_out, int out_size, void* d_ws, size_t ws_size,
                              hipStream_t stream) {
    const float* x   = (const float*)d_in[0];
    const int*   ei  = (const int*)d_in[1];
    const int*   src = ei;
    const int*   dst = ei + N_EDGES;
    const int*   batch = (const int*)d_in[2];
    const float* ea  = (const float*)d_in[3];
    const float* cw0 = (const float*)d_in[4];
    const float* cwr = (const float*)d_in[5];
    const float* cb  = (const float*)d_in[6];
    const float* lw  = (const float*)d_in[7];
    const float* lb  = (const float*)d_in[8];
    const float* w1  = (const float*)d_in[9];
    const float* b1  = (const float*)d_in[10];
    const float* w2  = (const float*)d_in[11];
    const float* b2  = (const float*)d_in[12];
    const float* w3  = (const float*)d_in[13];
    const float* b3  = (const float*)d_in[14];
    float* out = (float*)d_out;

    // workspace layout (4-byte units) — offsets kept identical to round 8 (validated)
    float* ws      = (float*)d_ws;
    float* dinv    = ws;                                   // 200000
    float* s1v     = ws + 200000;                          // 200000
    int*   blkhist = (int*)(ws + 400000);                  // reserve 2443750 (uses 611524)
    float2* db0    = (float2*)(ws + 400000);               // aliases blkhist; 400000 floats
    int*   bstart  = blkhist + 2443750;                    // 783 (pad 784)
    int*   nodeoff = bstart + 784;                         // 200000 (pad 200010)
    float* num     = (float*)(nodeoff + 200010);           // 16384
    float* den     = num + 16384;                          // 16384
    float* Mm      = den + 16384;                          // 288 (unused, keeps offsets)
    float2* dx     = (float2*)(Mm + 288);                  // 400000 floats (even offset)
    u64* bucketed  = (u64*)((float*)dx + 400000);          // E u64 (even offset)
    u64* sorted    = bucketed + N_EDGES;                   // E u64
    float* h2hat   = (float*)bucketed;                     // alias: free after sortd
    float* h3      = h2hat + (size_t)N_NODES * HD;         // alias (bucketed region)

    hipMemsetAsync(num, 0, (size_t)2 * N_GRAPHS * HD * sizeof(float), stream);

    // full sort by dst: radix pass 1 (bucket dst>>8), pass 2 (in-bucket dlow + dinv/dx)
    hist_kernel<<<NBLKA, 256, 0, stream>>>(dst, blkhist);
    scanA_kernel<<<NBUCK, 256, 0, stream>>>(blkhist, bstart);
    scanB_kernel<<<1, 256, 0, stream>>>(bstart);
    scatter_kernel<<<NBLKA, 256, 0, stream>>>(src, dst, ea, blkhist, bstart, bucketed);
    sortd_kernel<<<NBUCK, 256, 0, stream>>>(bucketed, bstart, x, sorted, nodeoff, dinv, dx);

    // layer 0 (read-only, scalar) -> db0={dinv,base0}, s1
    agg0_kernel<<<NBUCK, 256, 0, stream>>>(sorted, nodeoff, dx, db0, s1v);
    // layer 1 (thread-per-node + fused prep + 2-stage epilogue) -> h2hat
    agg1_kernel<<<NBUCK, 256, 0, stream>>>(sorted, nodeoff, db0, s1v,
                                           cw0, cb, lw, lb,
                                           cwr, cb + 16, lw + 256, lb + 16, h2hat);
    // layer 2 (64B-line gather, unroll-8, 4 nodes/group) -> h3
    agg2_kernel<<<3125, 256, 0, stream>>>(sorted, nodeoff, h2hat, dinv,
                                          cwr + 256, cb + 32, lw + 512, lb + 32, h3);

    pool_kernel<<<(N_NODES + 16 * POOL_RUN - 1) / (16 * POOL_RUN), 256, 0, stream>>>(h3, batch, num, den);
    final_kernel<<<(N_GRAPHS + 63) / 64, 64, 0, stream>>>(num, den, w1, b1, w2, b2, w3, b3, out);
}